// Round 1
// baseline (343.581 us; speedup 1.0000x reference)
//
#include <hip/hip_runtime.h>
#include <stdint.h>

#define BATCH 32
#define CCH   512
#define NPIX  1024
#define HEADS 8
#define QKV_M 1536   // q rows 0-511, k rows 512-1023, v rows 1024-1535

typedef short bf16x8 __attribute__((ext_vector_type(8)));
typedef float f32x4 __attribute__((ext_vector_type(4)));

__device__ inline float bf2f(unsigned short u) {
  union { float f; uint32_t i; } t; t.i = ((uint32_t)u) << 16; return t.f;
}
__device__ inline unsigned short f2bf(float f) {
  union { float f; uint32_t u; } t; t.f = f;
  uint32_t u = t.u;
  return (unsigned short)((u + 0x7FFFu + ((u >> 16) & 1u)) >> 16);
}

// async global->LDS, 16B per lane; LDS dest = wave-uniform base + lane*16
__device__ inline void gl_lds16(const unsigned short* g, unsigned short* l) {
  __builtin_amdgcn_global_load_lds(
      (const __attribute__((address_space(1))) uint32_t*)g,
      (__attribute__((address_space(3))) uint32_t*)l, 16, 0, 0);
}

// ---------------- weights fp32 -> bf16 (Wq|Wk|Wv concat, Wp separate) --------
__global__ void convert_w(const float* __restrict__ Wq, const float* __restrict__ Wk,
                          const float* __restrict__ Wv, const float* __restrict__ Wp,
                          unsigned short* __restrict__ wcat,
                          unsigned short* __restrict__ wpb) {
  int i = (blockIdx.x * 256 + threadIdx.x) * 4;   // over CCH*CCH = 262144
  union { ushort4 u4; unsigned short s[4]; } o;
  f32x4 a;
  a = *(const f32x4*)&Wq[i];
  for (int j = 0; j < 4; j++) o.s[j] = f2bf(a[j]);
  *(ushort4*)&wcat[i] = o.u4;
  a = *(const f32x4*)&Wk[i];
  for (int j = 0; j < 4; j++) o.s[j] = f2bf(a[j]);
  *(ushort4*)&wcat[CCH * CCH + i] = o.u4;
  a = *(const f32x4*)&Wv[i];
  for (int j = 0; j < 4; j++) o.s[j] = f2bf(a[j]);
  *(ushort4*)&wcat[2 * CCH * CCH + i] = o.u4;
  a = *(const f32x4*)&Wp[i];
  for (int j = 0; j < 4; j++) o.s[j] = f2bf(a[j]);
  *(ushort4*)&wpb[i] = o.u4;
}

// ---------------- transpose fp32 [b,R,Cc] -> bf16 [b,Cc,R] -------------------
__global__ void transpose_f2b(const float* __restrict__ in,
                              unsigned short* __restrict__ out, int R, int Cc) {
  __shared__ float tile[32][33];
  int b = blockIdx.z;
  int c0 = blockIdx.x * 32;
  int r0 = blockIdx.y * 32;
  const float* inb = in + (size_t)b * R * Cc;
  unsigned short* outb = out + (size_t)b * R * Cc;
  int tx = threadIdx.x, ty = threadIdx.y;
  for (int i = 0; i < 4; i++) {
    int r = ty + i * 8;
    tile[r][tx] = inb[(size_t)(r0 + r) * Cc + c0 + tx];
  }
  __syncthreads();
  for (int i = 0; i < 4; i++) {
    int r = ty + i * 8;
    outb[(size_t)(c0 + r) * R + r0 + tx] = f2bf(tile[tx][r]);
  }
}

// ---------------- gemm_bt: C[b][m][n] = sum_k A[m][k]*X[b][n][k] -------------
// 256x256 tile, BK=64, 512 threads = 8 waves (2 M x 4 N), mfma 16x16x32.
// Double-buffered LDS (128 KiB), global_load_lds staging with XOR chunk
// swizzle (proven conflict-free: SQ_LDS_BANK_CONFLICT==0 on the 128^2 kernel).
// Pipeline (T3+T4): at first phase of K-tile t, issue all 8 loads for tile
// t+1 into the buffer freed at end of tile t-1, then s_waitcnt vmcnt(8)
// (counted -- next tile's loads stay in flight) + raw s_barrier to publish.
// 4 phases per K-tile (one C-quadrant each): 12 ds_read_b128 -> barrier ->
// lgkmcnt(0) -> setprio(1) -> 16 MFMA -> setprio(0) -> barrier (T5).
template <bool OUT_F32>
__launch_bounds__(512, 2)
__global__ void gemm_bt(const unsigned short* __restrict__ A,
                        const unsigned short* __restrict__ X,
                        void* __restrict__ Cout,
                        const float* __restrict__ bias,
                        int M, int N, int K) {
  __shared__ __align__(16) unsigned short As[2][256 * 64];
  __shared__ __align__(16) unsigned short Bs[2][256 * 64];
  const int b  = blockIdx.z;
  const int m0 = blockIdx.y * 256;
  const int n0 = blockIdx.x * 256;
  const unsigned short* Xb = X + (size_t)b * N * K;
  const int tid  = threadIdx.x;
  const int lane = tid & 63;
  const int wave = tid >> 6;        // 0..7
  const int wm = wave >> 2;         // 0..1  (M half: 128 rows each)
  const int wn = wave & 3;          // 0..3  (N quarter: 64 cols each)
  const int quad = lane >> 4, l16 = lane & 15;

  f32x4 acc[8][4];
  const f32x4 zero = {0.f, 0.f, 0.f, 0.f};
#pragma unroll
  for (int i = 0; i < 8; i++)
#pragma unroll
    for (int j = 0; j < 4; j++) acc[i][j] = zero;

  // staging geometry: wave w covers rows [w*32, w*32+32), 4 loads of 8 rows
  // per matrix. lane -> row += lane>>3; fetched k-chunk = (lane&7)^(lane>>3)
  // (XOR swizzle; still one 128B segment per 8-lane row-group -> coalesced).
  const int r8  = lane >> 3;
  const int swk = ((lane & 7) ^ r8) * 8;
  const unsigned short* Ag = A  + (size_t)(m0 + wave * 32 + r8) * K + swk;
  const unsigned short* Xg = Xb + (size_t)(n0 + wave * 32 + r8) * K + swk;

  const int NT = K >> 6;            // K-tiles of 64

  auto stage = [&](int kt, int bsel) {
    unsigned short* Al = &As[bsel][wave * 32 * 64];
    unsigned short* Bl = &Bs[bsel][wave * 32 * 64];
    const unsigned short* Agk = Ag + kt * 64;
    const unsigned short* Xgk = Xg + kt * 64;
#pragma unroll
    for (int i = 0; i < 4; ++i) {
      gl_lds16(Agk + (size_t)i * 8 * K, Al + i * 8 * 64);
      gl_lds16(Xgk + (size_t)i * 8 * K, Bl + i * 8 * 64);
    }
  };

  stage(0, 0);                       // 8 loads in flight
  for (int t = 0; t < NT; ++t) {
    const int cur = t & 1;
    if (t + 1 < NT) {
      // buffer cur^1 was last read for tile t-1; all those reads completed
      // before the closing barrier of iteration t-1 -> safe to overwrite.
      stage(t + 1, cur ^ 1);
      asm volatile("s_waitcnt vmcnt(8)" ::: "memory");   // tile t landed
    } else {
      asm volatile("s_waitcnt vmcnt(0)" ::: "memory");   // final drain
    }
    __builtin_amdgcn_s_barrier();    // publish tile t to all waves
    const unsigned short* Asl = As[cur];
    const unsigned short* Bsl = Bs[cur];
#pragma unroll
    for (int ph = 0; ph < 4; ++ph) {
      const int Qm = ph >> 1, Qn = ph & 1;   // C-quadrant of this phase
      bf16x8 af[4][2], bfr[2][2];
      // fragment read: logical chunk (ks*4+quad) lives at physical ^(l16&7)
#pragma unroll
      for (int ii = 0; ii < 4; ++ii)
#pragma unroll
        for (int ks = 0; ks < 2; ++ks) {
          const int row = wm * 128 + (Qm * 4 + ii) * 16 + l16;
          const int ch  = ((ks * 4 + quad) ^ (l16 & 7)) * 8;
          af[ii][ks] = *(const bf16x8*)&Asl[row * 64 + ch];
        }
#pragma unroll
      for (int jj = 0; jj < 2; ++jj)
#pragma unroll
        for (int ks = 0; ks < 2; ++ks) {
          const int row = wn * 64 + (Qn * 2 + jj) * 16 + l16;
          const int ch  = ((ks * 4 + quad) ^ (l16 & 7)) * 8;
          bfr[jj][ks] = *(const bf16x8*)&Bsl[row * 64 + ch];
        }
      __builtin_amdgcn_s_barrier();
      asm volatile("s_waitcnt lgkmcnt(0)" ::: "memory");
      __builtin_amdgcn_sched_barrier(0);     // rule #18: fence MFMA hoisting
      __builtin_amdgcn_s_setprio(1);
#pragma unroll
      for (int ks = 0; ks < 2; ++ks)
#pragma unroll
        for (int ii = 0; ii < 4; ++ii)
#pragma unroll
          for (int jj = 0; jj < 2; ++jj)
            acc[Qm * 4 + ii][Qn * 2 + jj] =
                __builtin_amdgcn_mfma_f32_16x16x32_bf16(
                    af[ii][ks], bfr[jj][ks],
                    acc[Qm * 4 + ii][Qn * 2 + jj], 0, 0, 0);
      __builtin_amdgcn_s_setprio(0);
      __builtin_amdgcn_s_barrier();
    }
  }

  // C/D layout: row = quad*4+reg, col = l16
#pragma unroll
  for (int i = 0; i < 8; ++i) {
#pragma unroll
    for (int r = 0; r < 4; ++r) {
      const int gm = m0 + wm * 128 + i * 16 + quad * 4 + r;
      if constexpr (OUT_F32) {
        const float bv = bias[gm];
        float* Co = (float*)Cout + (size_t)b * M * N + (size_t)gm * N +
                    n0 + wn * 64 + l16;
#pragma unroll
        for (int j = 0; j < 4; ++j) Co[j * 16] = acc[i][j][r] + bv;
      } else {
        unsigned short* Co = (unsigned short*)Cout + (size_t)b * M * N +
                             (size_t)gm * N + n0 + wn * 64 + l16;
#pragma unroll
        for (int j = 0; j < 4; ++j) Co[j * 16] = f2bf(acc[i][j][r]);
      }
    }
  }
}

// ---------------- depthwise 3x3 per-channel stats (sum, sumsq) ---------------
__global__ void dw_stats(const float* __restrict__ x,
                         const float* __restrict__ wgt,
                         float* __restrict__ s1, float* __restrict__ s2) {
  int c = blockIdx.x, b = blockIdx.y;
  __shared__ __align__(16) float plane[NPIX];
  const float* xp = x + ((size_t)b * CCH + c) * NPIX;
  *(f32x4*)&plane[threadIdx.x * 4] = *(const f32x4*)&xp[threadIdx.x * 4];
  __syncthreads();
  float w[9];
  for (int i = 0; i < 9; i++) w[i] = wgt[c * 9 + i];
  float a1 = 0.f, a2 = 0.f;
  for (int pi = 0; pi < 4; pi++) {
    int p = threadIdx.x + pi * 256;
    int h = p >> 5, wc = p & 31;
    float v = 0.f;
    for (int dh = -1; dh <= 1; dh++)
      for (int dw = -1; dw <= 1; dw++) {
        int hh = h + dh, ww = wc + dw;
        if (hh >= 0 && hh < 32 && ww >= 0 && ww < 32)
          v += w[(dh + 1) * 3 + dw + 1] * plane[hh * 32 + ww];
      }
    a1 += v; a2 += v * v;
  }
  for (int off = 32; off > 0; off >>= 1) {
    a1 += __shfl_down(a1, off);
    a2 += __shfl_down(a2, off);
  }
  __shared__ float r1[4], r2[4];
  int wv = threadIdx.x >> 6;
  if ((threadIdx.x & 63) == 0) { r1[wv] = a1; r2[wv] = a2; }
  __syncthreads();
  if (threadIdx.x == 0) {
    atomicAdd(&s1[c], r1[0] + r1[1] + r1[2] + r1[3]);
    atomicAdd(&s2[c], r2[0] + r2[1] + r2[2] + r2[3]);
  }
}

// ---------------- gate: v (rows 1024..1535 of qkv) *= SiLU(BN(conv(x))) ------
__global__ void gate_apply(const float* __restrict__ x,
                           const float* __restrict__ wgt,
                           const float* __restrict__ s1, const float* __restrict__ s2,
                           const float* __restrict__ gamma,
                           const float* __restrict__ beta,
                           unsigned short* __restrict__ qkv) {
  int c = blockIdx.x, b = blockIdx.y;
  __shared__ __align__(16) float plane[NPIX];
  const float* xp = x + ((size_t)b * CCH + c) * NPIX;
  unsigned short* vp = qkv + ((size_t)b * QKV_M + 2 * CCH + c) * NPIX;
  *(f32x4*)&plane[threadIdx.x * 4] = *(const f32x4*)&xp[threadIdx.x * 4];
  __syncthreads();
  float w[9];
  for (int i = 0; i < 9; i++) w[i] = wgt[c * 9 + i];
  const float invn = 1.f / 32768.f;
  float mean = s1[c] * invn;
  float var = fmaxf(s2[c] * invn - mean * mean, 0.f);
  float rstd = rsqrtf(var + 1e-5f);
  float ga = gamma[c], be = beta[c];
  for (int pi = 0; pi < 4; pi++) {
    int p = threadIdx.x + pi * 256;
    int h = p >> 5, wc = p & 31;
    float val = 0.f;
    for (int dh = -1; dh <= 1; dh++)
      for (int dw = -1; dw <= 1; dw++) {
        int hh = h + dh, ww = wc + dw;
        if (hh >= 0 && hh < 32 && ww >= 0 && ww < 32)
          val += w[(dh + 1) * 3 + dw + 1] * plane[hh * 32 + ww];
      }
    float g = (val - mean) * rstd * ga + be;
    float sg = g / (1.f + __expf(-g));      // SiLU
    vp[p] = f2bf(bf2f(vp[p]) * sg);
  }
}

// ---------------- attn_s: S=QK^T (+ fused l2norm via QQ^T/KK^T diag),
//                  softmax -> P [bh][64][64] bf16 -------------------------------
__launch_bounds__(256)
__global__ void attn_s(const unsigned short* __restrict__ qkv,
                       const float* __restrict__ temp,
                       unsigned short* __restrict__ P) {
  int bh = blockIdx.x;
  int b = bh >> 3, h = bh & 7;
  const unsigned short* Q = qkv + ((size_t)b * QKV_M + h * 64) * NPIX;
  const unsigned short* K = Q + (size_t)CCH * NPIX;
  int tid = threadIdx.x, lane = tid & 63, wave = tid >> 6;
  int quad = lane >> 4, l16 = lane & 15;

  __shared__ __align__(16) float Sf[64][65];
  __shared__ float qq[64], kk[64], invq[64], invk[64];
  __shared__ float redm[4][64], reds[4][64];

  f32x4 zero = {0.f, 0.f, 0.f, 0.f};
  f32x4 acc[4], accQ = zero, accK = zero;
  for (int j = 0; j < 4; j++) acc[j] = zero;
  for (int n0 = 0; n0 < NPIX; n0 += 32) {
    bf16x8 a  = *(const bf16x8*)&Q[(size_t)(wave * 16 + l16) * NPIX + n0 + quad * 8];
    bf16x8 ak = *(const bf16x8*)&K[(size_t)(wave * 16 + l16) * NPIX + n0 + quad * 8];
    accQ = __builtin_amdgcn_mfma_f32_16x16x32_bf16(a, a, accQ, 0, 0, 0);
    accK = __builtin_amdgcn_mfma_f32_16x16x32_bf16(ak, ak, accK, 0, 0, 0);
    for (int j = 0; j < 4; j++) {
      bf16x8 bb = *(const bf16x8*)&K[(size_t)(j * 16 + l16) * NPIX + n0 + quad * 8];
      acc[j] = __builtin_amdgcn_mfma_f32_16x16x32_bf16(a, bb, acc[j], 0, 0, 0);
    }
  }
  for (int j = 0; j < 4; j++)
    for (int r = 0; r < 4; r++)
      Sf[wave * 16 + quad * 4 + r][j * 16 + l16] = acc[j][r];
  // diagonal of Q.Q^T / K.K^T: D row=quad*4+r, col=l16 -> diag where equal
  for (int r = 0; r < 4; r++)
    if (l16 == quad * 4 + r) {
      qq[wave * 16 + l16] = accQ[r];
      kk[wave * 16 + l16] = accK[r];
    }
  __syncthreads();
  if (tid < 64) invq[tid] = 1.f / fmaxf(sqrtf(qq[tid]), 1e-12f);
  else if (tid < 128) invk[tid - 64] = 1.f / fmaxf(sqrtf(kk[tid - 64]), 1e-12f);
  __syncthreads();

  // softmax over e: 256 threads = 64 rows x 4 segments of 16
  int row = tid & 63, seg = tid >> 6;
  float fq = temp[h] * invq[row];
  float v[16], pm = -1e30f;
  for (int i = 0; i < 16; i++) {
    v[i] = Sf[row][seg * 16 + i] * fq * invk[seg * 16 + i];
    pm = fmaxf(pm, v[i]);
  }
  redm[seg][row] = pm;
  __syncthreads();
  float m = fmaxf(fmaxf(redm[0][row], redm[1][row]),
                  fmaxf(redm[2][row], redm[3][row]));
  float ps = 0.f;
  for (int i = 0; i < 16; i++) { v[i] = __expf(v[i] - m); ps += v[i]; }
  reds[seg][row] = ps;
  __syncthreads();
  float inv = 1.f / (reds[0][row] + reds[1][row] + reds[2][row] + reds[3][row]);
  union { uint4 q4[2]; unsigned short s[16]; } u;
  for (int i = 0; i < 16; i++) u.s[i] = f2bf(v[i] * inv);
  unsigned short* Pp = P + ((size_t)bh * 64 + row) * 64 + seg * 16;
  *(uint4*)&Pp[0] = u.q4[0];
  *(uint4*)&Pp[8] = u.q4[1];
}

// ---------------- attn_o: O^T[n][d] = sum_e V^T[n][e] P[d][e] ----------------
// grid = bh*4 (n-quarters); register-prefetched V, LDS-staged coalesced stores.
__launch_bounds__(256)
__global__ void attn_o(const unsigned short* __restrict__ qkv,
                       const unsigned short* __restrict__ P,
                       unsigned short* __restrict__ aoT) {
  int blk = blockIdx.x;
  int nc = blk & 3, bh = blk >> 2;
  int b = bh >> 3, h = bh & 7;
  const unsigned short* V = qkv + ((size_t)b * QKV_M + 2 * CCH + h * 64) * NPIX;
  unsigned short* Ob = aoT + (size_t)b * NPIX * CCH + h * 64;
  int tid = threadIdx.x, lane = tid & 63, wave = tid >> 6;
  int quad = lane >> 4, l16 = lane & 15;

  __shared__ __align__(16) unsigned short Vt[4][16][72];
  __shared__ __align__(16) unsigned short Ot[4][16][72];

  // P fragments (B-operand: row d = j*16+l16, k = e)
  const unsigned short* Pb = P + (size_t)bh * 64 * 64;
  bf16x8 Pf[4][2];
  for (int j = 0; j < 4; j++)
    for (int ks = 0; ks < 2; ks++)
      Pf[j][ks] = *(const bf16x8*)&Pb[(j * 16 + l16) * 64 + ks * 32 + quad * 8];

  f32x4 zero = {0.f, 0.f, 0.f, 0.f};
  int e1 = lane >> 1, noff = (lane & 1) * 8;
  int nbase = nc * 256 + wave * 64;
  int orow = lane >> 3, ocol = (lane & 7) * 8;

  union { uint4 q; unsigned short s[8]; } g0, g1, c0, c1;
  g0.q = *(const uint4*)&V[(size_t)e1 * NPIX + nbase + noff];
  g1.q = *(const uint4*)&V[(size_t)(e1 + 32) * NPIX + nbase + noff];
#pragma unroll
  for (int nt = 0; nt < 4; nt++) {
    int n0 = nbase + nt * 16;
    c0 = g0; c1 = g1;
    if (nt < 3) {
      g0.q = *(const uint4*)&V[(size_t)e1 * NPIX + n0 + 16 + noff];
      g1.q = *(const uint4*)&V[(size_t)(e1 + 32) * NPIX + n0 + 16 + noff];
    }
    for (int jj = 0; jj < 8; jj++) {
      Vt[wave][noff + jj][e1]      = c0.s[jj];
      Vt[wave][noff + jj][e1 + 32] = c1.s[jj];
    }
    bf16x8 Af0 = *(const bf16x8*)&Vt[wave][l16][quad * 8];
    bf16x8 Af1 = *(const bf16x8*)&Vt[wave][l16][32 + quad * 8];
    f32x4 oacc[4];
    for (int j = 0; j < 4; j++) {
      oacc[j] = __builtin_amdgcn_mfma_f32_16x16x32_bf16(Af0, Pf[j][0], zero, 0, 0, 0);
      oacc[j] = __builtin_amdgcn_mfma_f32_16x16x32_bf16(Af1, Pf[j][1], oacc[j], 0, 0, 0);
    }
    for (int j = 0; j < 4; j++)
      for (int r = 0; r < 4; r++)
        Ot[wave][quad * 4 + r][j * 16 + l16] = f2bf(oacc[j][r]);
    uint4 o0 = *(const uint4*)&Ot[wave][orow][ocol];
    uint4 o1 = *(const uint4*)&Ot[wave][orow + 8][ocol];
    *(uint4*)&Ob[(size_t)(n0 + orow) * CCH + ocol] = o0;
    *(uint4*)&Ob[(size_t)(n0 + orow + 8) * CCH + ocol] = o1;
  }
}

// ---------------------------------------------------------------------------
extern "C" void kernel_launch(void* const* d_in, const int* in_sizes, int n_in,
                              void* d_out, int out_size, void* d_ws, size_t ws_size,
                              hipStream_t stream) {
  const float* x     = (const float*)d_in[0];
  const float* Wq    = (const float*)d_in[1];
  const float* Wk    = (const float*)d_in[2];
  const float* Wv    = (const float*)d_in[3];
  const float* dww   = (const float*)d_in[4];
  const float* gamma = (const float*)d_in[5];
  const float* beta  = (const float*)d_in[6];
  const float* temp  = (const float*)d_in[7];
  const float* Wp    = (const float*)d_in[8];
  const float* bp    = (const float*)d_in[9];
  float* out = (float*)d_out;

  char* ws = (char*)d_ws;
  unsigned short* wcat = (unsigned short*)ws;             // [1536,512] bf16
  unsigned short* wpb  = wcat + (size_t)QKV_M * CCH;      // [512,512] bf16
  float* s1 = (float*)(wpb + (size_t)CCH * CCH);
  float* s2 = s1 + CCH;
  unsigned short* Pbuf = (unsigned short*)(s2 + CCH);     // [B*H,64,64] bf16, 2MB
  char* dyn = (char*)(Pbuf + (size_t)BATCH * HEADS * 64 * 64);
  size_t fixed = (size_t)(dyn - ws);
  size_t per_b = ((size_t)NPIX * CCH + (size_t)QKV_M * NPIX) * 2;  // 4 MB/batch
  int BC = BATCH;
  while (BC > 1 && fixed + (size_t)BC * per_b > ws_size) BC >>= 1;
  unsigned short* xT  = (unsigned short*)dyn;                  // [BC,N,C]; reused as aoT
  unsigned short* qkv = xT + (size_t)BC * NPIX * CCH;          // [BC,1536,N]

  convert_w<<<CCH * CCH / 1024, 256, 0, stream>>>(Wq, Wk, Wv, Wp, wcat, wpb);
  hipMemsetAsync(s1, 0, 2 * CCH * sizeof(float), stream);
  dw_stats<<<dim3(CCH, BATCH), 256, 0, stream>>>(x, dww, s1, s2);

  for (int b0 = 0; b0 < BATCH; b0 += BC) {
    const float* xc = x + (size_t)b0 * CCH * NPIX;
    float* outc = out + (size_t)b0 * CCH * NPIX;
    transpose_f2b<<<dim3(NPIX / 32, CCH / 32, BC), dim3(32, 8), 0, stream>>>(
        xc, xT, CCH, NPIX);
    gemm_bt<false><<<dim3(NPIX / 256, QKV_M / 256, BC), 512, 0, stream>>>(
        wcat, xT, qkv, nullptr, QKV_M, NPIX, CCH);
    attn_s<<<BC * HEADS, 256, 0, stream>>>(qkv, temp, Pbuf);
    gate_apply<<<dim3(CCH, BC), 256, 0, stream>>>(xc, dww, s1, s2, gamma, beta, qkv);
    attn_o<<<BC * HEADS * 4, 256, 0, stream>>>(qkv, Pbuf, xT);  // aoT overwrites xT
    gemm_bt<true><<<dim3(NPIX / 256, CCH / 256, BC), 512, 0, stream>>>(
        wpb, xT, outc, bp, CCH, NPIX, CCH);
  }
}

// Round 2
// 332.697 us; speedup vs baseline: 1.0327x; 1.0327x over previous
//
#include <hip/hip_runtime.h>
#include <stdint.h>

#define BATCH 32
#define CCH   512
#define NPIX  1024
#define HEADS 8
#define QKV_M 1536   // q rows 0-511, k rows 512-1023, v rows 1024-1535

typedef short bf16x8 __attribute__((ext_vector_type(8)));
typedef float f32x4 __attribute__((ext_vector_type(4)));

__device__ inline float bf2f(unsigned short u) {
  union { float f; uint32_t i; } t; t.i = ((uint32_t)u) << 16; return t.f;
}
__device__ inline unsigned short f2bf(float f) {
  union { float f; uint32_t u; } t; t.f = f;
  uint32_t u = t.u;
  return (unsigned short)((u + 0x7FFFu + ((u >> 16) & 1u)) >> 16);
}

// async global->LDS, 16B per lane; LDS dest = wave-uniform base + lane*16
__device__ inline void gl_lds16(const unsigned short* g, unsigned short* l) {
  __builtin_amdgcn_global_load_lds(
      (const __attribute__((address_space(1))) uint32_t*)g,
      (__attribute__((address_space(3))) uint32_t*)l, 16, 0, 0);
}

// ---------------- weights fp32 -> bf16 (Wq|Wk|Wv concat, Wp separate) --------
__global__ void convert_w(const float* __restrict__ Wq, const float* __restrict__ Wk,
                          const float* __restrict__ Wv, const float* __restrict__ Wp,
                          unsigned short* __restrict__ wcat,
                          unsigned short* __restrict__ wpb) {
  int i = (blockIdx.x * 256 + threadIdx.x) * 4;   // over CCH*CCH = 262144
  union { ushort4 u4; unsigned short s[4]; } o;
  f32x4 a;
  a = *(const f32x4*)&Wq[i];
  for (int j = 0; j < 4; j++) o.s[j] = f2bf(a[j]);
  *(ushort4*)&wcat[i] = o.u4;
  a = *(const f32x4*)&Wk[i];
  for (int j = 0; j < 4; j++) o.s[j] = f2bf(a[j]);
  *(ushort4*)&wcat[CCH * CCH + i] = o.u4;
  a = *(const f32x4*)&Wv[i];
  for (int j = 0; j < 4; j++) o.s[j] = f2bf(a[j]);
  *(ushort4*)&wcat[2 * CCH * CCH + i] = o.u4;
  a = *(const f32x4*)&Wp[i];
  for (int j = 0; j < 4; j++) o.s[j] = f2bf(a[j]);
  *(ushort4*)&wpb[i] = o.u4;
}

// ---------------- transpose fp32 [b,R,Cc] -> bf16 [b,Cc,R] -------------------
__global__ void transpose_f2b(const float* __restrict__ in,
                              unsigned short* __restrict__ out, int R, int Cc) {
  __shared__ float tile[32][33];
  int b = blockIdx.z;
  int c0 = blockIdx.x * 32;
  int r0 = blockIdx.y * 32;
  const float* inb = in + (size_t)b * R * Cc;
  unsigned short* outb = out + (size_t)b * R * Cc;
  int tx = threadIdx.x, ty = threadIdx.y;
  for (int i = 0; i < 4; i++) {
    int r = ty + i * 8;
    tile[r][tx] = inb[(size_t)(r0 + r) * Cc + c0 + tx];
  }
  __syncthreads();
  for (int i = 0; i < 4; i++) {
    int r = ty + i * 8;
    outb[(size_t)(c0 + r) * R + r0 + tx] = f2bf(tile[tx][r]);
  }
}

// ---------------- gemm_bt: C[b][m][n] = sum_k A[m][k]*X[b][n][k] -------------
// 256x256 tile, BK=64, 512 threads = 8 waves (2 M x 4 N), mfma 16x16x32.
// Double-buffered LDS (128 KiB), global_load_lds staging with XOR chunk
// swizzle (conflict-free ds_read_b128: SQ_LDS_BANK_CONFLICT==0 measured).
// Pipeline (T3+T4): at top of K-tile t, issue all 8 loads for tile t+1 into
// the buffer freed at end of tile t-1, then s_waitcnt vmcnt(8) (counted --
// next tile's loads stay in flight) + s_barrier to publish tile t.
// 2 phases per K-tile keyed on the K-SLICE ks (NOT the C-quadrant): phase ks
// reads each fragment exactly ONCE (8 A + 4 B ds_read_b128) then fires the
// full 32-MFMA cluster (8m x 4n) under setprio (T5). Round-1 post-mortem:
// quadrant-keyed phases re-read every fragment twice -> 2x LDS traffic ->
// LDS-read-bound at MfmaUtil 23%. This schedule is non-redundant: 24
// ds_read_b128 / wave / K-tile, LDS pipe ~= MFMA pipe.
template <bool OUT_F32>
__launch_bounds__(512, 2)
__global__ void gemm_bt(const unsigned short* __restrict__ A,
                        const unsigned short* __restrict__ X,
                        void* __restrict__ Cout,
                        const float* __restrict__ bias,
                        int M, int N, int K) {
  __shared__ __align__(16) unsigned short As[2][256 * 64];
  __shared__ __align__(16) unsigned short Bs[2][256 * 64];
  const int b  = blockIdx.z;
  const int m0 = blockIdx.y * 256;
  const int n0 = blockIdx.x * 256;
  const unsigned short* Xb = X + (size_t)b * N * K;
  const int tid  = threadIdx.x;
  const int lane = tid & 63;
  const int wave = tid >> 6;        // 0..7
  const int wm = wave >> 2;         // 0..1  (M half: 128 rows each)
  const int wn = wave & 3;          // 0..3  (N quarter: 64 cols each)
  const int quad = lane >> 4, l16 = lane & 15;

  f32x4 acc[8][4];
  const f32x4 zero = {0.f, 0.f, 0.f, 0.f};
#pragma unroll
  for (int i = 0; i < 8; i++)
#pragma unroll
    for (int j = 0; j < 4; j++) acc[i][j] = zero;

  // staging geometry: wave w covers rows [w*32, w*32+32), 4 loads of 8 rows
  // per matrix. lane -> row += lane>>3; fetched k-chunk = (lane&7)^(lane>>3)
  // (XOR swizzle; still one 128B segment per 8-lane row-group -> coalesced).
  const int r8  = lane >> 3;
  const int swk = ((lane & 7) ^ r8) * 8;
  const unsigned short* Ag = A  + (size_t)(m0 + wave * 32 + r8) * K + swk;
  const unsigned short* Xg = Xb + (size_t)(n0 + wave * 32 + r8) * K + swk;

  const int NT = K >> 6;            // K-tiles of 64

  auto stage = [&](int kt, int bsel) {
    unsigned short* Al = &As[bsel][wave * 32 * 64];
    unsigned short* Bl = &Bs[bsel][wave * 32 * 64];
    const unsigned short* Agk = Ag + kt * 64;
    const unsigned short* Xgk = Xg + kt * 64;
#pragma unroll
    for (int i = 0; i < 4; ++i) {
      gl_lds16(Agk + (size_t)i * 8 * K, Al + i * 8 * 64);
      gl_lds16(Xgk + (size_t)i * 8 * K, Bl + i * 8 * 64);
    }
  };

  stage(0, 0);                       // 8 loads in flight
  for (int t = 0; t < NT; ++t) {
    const int cur = t & 1;
    if (t + 1 < NT) {
      // buffer cur^1 was last read for tile t-1; all those reads completed
      // before the closing barrier of iteration t-1 -> safe to overwrite.
      stage(t + 1, cur ^ 1);
      asm volatile("s_waitcnt vmcnt(8)" ::: "memory");   // tile t landed
    } else {
      asm volatile("s_waitcnt vmcnt(0)" ::: "memory");   // final drain
    }
    __builtin_amdgcn_s_barrier();    // publish tile t to all waves
    const unsigned short* Asl = As[cur];
    const unsigned short* Bsl = Bs[cur];
#pragma unroll
    for (int ks = 0; ks < 2; ++ks) {
      // fragment read: logical chunk (ks*4+quad) lives at physical ^(l16&7)
      const int ch = ((ks * 4 + quad) ^ (l16 & 7)) * 8;
      bf16x8 af[8], bfr[4];
#pragma unroll
      for (int ii = 0; ii < 8; ++ii)
        af[ii] = *(const bf16x8*)&Asl[(wm * 128 + ii * 16 + l16) * 64 + ch];
#pragma unroll
      for (int jj = 0; jj < 4; ++jj)
        bfr[jj] = *(const bf16x8*)&Bsl[(wn * 64 + jj * 16 + l16) * 64 + ch];
      __builtin_amdgcn_s_barrier();
      asm volatile("s_waitcnt lgkmcnt(0)" ::: "memory");
      __builtin_amdgcn_sched_barrier(0);     // rule #18: fence MFMA hoisting
      __builtin_amdgcn_s_setprio(1);
#pragma unroll
      for (int ii = 0; ii < 8; ++ii)
#pragma unroll
        for (int jj = 0; jj < 4; ++jj)
          acc[ii][jj] = __builtin_amdgcn_mfma_f32_16x16x32_bf16(
              af[ii], bfr[jj], acc[ii][jj], 0, 0, 0);
      __builtin_amdgcn_s_setprio(0);
      __builtin_amdgcn_s_barrier();
    }
  }

  // C/D layout: row = quad*4+reg, col = l16
#pragma unroll
  for (int i = 0; i < 8; ++i) {
#pragma unroll
    for (int r = 0; r < 4; ++r) {
      const int gm = m0 + wm * 128 + i * 16 + quad * 4 + r;
      if constexpr (OUT_F32) {
        const float bv = bias[gm];
        float* Co = (float*)Cout + (size_t)b * M * N + (size_t)gm * N +
                    n0 + wn * 64 + l16;
#pragma unroll
        for (int j = 0; j < 4; ++j) Co[j * 16] = acc[i][j][r] + bv;
      } else {
        unsigned short* Co = (unsigned short*)Cout + (size_t)b * M * N +
                             (size_t)gm * N + n0 + wn * 64 + l16;
#pragma unroll
        for (int j = 0; j < 4; ++j) Co[j * 16] = f2bf(acc[i][j][r]);
      }
    }
  }
}

// ---------------- depthwise 3x3 per-channel stats (sum, sumsq) ---------------
__global__ void dw_stats(const float* __restrict__ x,
                         const float* __restrict__ wgt,
                         float* __restrict__ s1, float* __restrict__ s2) {
  int c = blockIdx.x, b = blockIdx.y;
  __shared__ __align__(16) float plane[NPIX];
  const float* xp = x + ((size_t)b * CCH + c) * NPIX;
  *(f32x4*)&plane[threadIdx.x * 4] = *(const f32x4*)&xp[threadIdx.x * 4];
  __syncthreads();
  float w[9];
  for (int i = 0; i < 9; i++) w[i] = wgt[c * 9 + i];
  float a1 = 0.f, a2 = 0.f;
  for (int pi = 0; pi < 4; pi++) {
    int p = threadIdx.x + pi * 256;
    int h = p >> 5, wc = p & 31;
    float v = 0.f;
    for (int dh = -1; dh <= 1; dh++)
      for (int dw = -1; dw <= 1; dw++) {
        int hh = h + dh, ww = wc + dw;
        if (hh >= 0 && hh < 32 && ww >= 0 && ww < 32)
          v += w[(dh + 1) * 3 + dw + 1] * plane[hh * 32 + ww];
      }
    a1 += v; a2 += v * v;
  }
  for (int off = 32; off > 0; off >>= 1) {
    a1 += __shfl_down(a1, off);
    a2 += __shfl_down(a2, off);
  }
  __shared__ float r1[4], r2[4];
  int wv = threadIdx.x >> 6;
  if ((threadIdx.x & 63) == 0) { r1[wv] = a1; r2[wv] = a2; }
  __syncthreads();
  if (threadIdx.x == 0) {
    atomicAdd(&s1[c], r1[0] + r1[1] + r1[2] + r1[3]);
    atomicAdd(&s2[c], r2[0] + r2[1] + r2[2] + r2[3]);
  }
}

// ---------------- gate: v (rows 1024..1535 of qkv) *= SiLU(BN(conv(x))) ------
__global__ void gate_apply(const float* __restrict__ x,
                           const float* __restrict__ wgt,
                           const float* __restrict__ s1, const float* __restrict__ s2,
                           const float* __restrict__ gamma,
                           const float* __restrict__ beta,
                           unsigned short* __restrict__ qkv) {
  int c = blockIdx.x, b = blockIdx.y;
  __shared__ __align__(16) float plane[NPIX];
  const float* xp = x + ((size_t)b * CCH + c) * NPIX;
  unsigned short* vp = qkv + ((size_t)b * QKV_M + 2 * CCH + c) * NPIX;
  *(f32x4*)&plane[threadIdx.x * 4] = *(const f32x4*)&xp[threadIdx.x * 4];
  __syncthreads();
  float w[9];
  for (int i = 0; i < 9; i++) w[i] = wgt[c * 9 + i];
  const float invn = 1.f / 32768.f;
  float mean = s1[c] * invn;
  float var = fmaxf(s2[c] * invn - mean * mean, 0.f);
  float rstd = rsqrtf(var + 1e-5f);
  float ga = gamma[c], be = beta[c];
  for (int pi = 0; pi < 4; pi++) {
    int p = threadIdx.x + pi * 256;
    int h = p >> 5, wc = p & 31;
    float val = 0.f;
    for (int dh = -1; dh <= 1; dh++)
      for (int dw = -1; dw <= 1; dw++) {
        int hh = h + dh, ww = wc + dw;
        if (hh >= 0 && hh < 32 && ww >= 0 && ww < 32)
          val += w[(dh + 1) * 3 + dw + 1] * plane[hh * 32 + ww];
      }
    float g = (val - mean) * rstd * ga + be;
    float sg = g / (1.f + __expf(-g));      // SiLU
    vp[p] = f2bf(bf2f(vp[p]) * sg);
  }
}

// ---------------- attn_s: S=QK^T (+ fused l2norm via QQ^T/KK^T diag),
//                  softmax -> P [bh][64][64] bf16 -------------------------------
__launch_bounds__(256)
__global__ void attn_s(const unsigned short* __restrict__ qkv,
                       const float* __restrict__ temp,
                       unsigned short* __restrict__ P) {
  int bh = blockIdx.x;
  int b = bh >> 3, h = bh & 7;
  const unsigned short* Q = qkv + ((size_t)b * QKV_M + h * 64) * NPIX;
  const unsigned short* K = Q + (size_t)CCH * NPIX;
  int tid = threadIdx.x, lane = tid & 63, wave = tid >> 6;
  int quad = lane >> 4, l16 = lane & 15;

  __shared__ __align__(16) float Sf[64][65];
  __shared__ float qq[64], kk[64], invq[64], invk[64];
  __shared__ float redm[4][64], reds[4][64];

  f32x4 zero = {0.f, 0.f, 0.f, 0.f};
  f32x4 acc[4], accQ = zero, accK = zero;
  for (int j = 0; j < 4; j++) acc[j] = zero;
  for (int n0 = 0; n0 < NPIX; n0 += 32) {
    bf16x8 a  = *(const bf16x8*)&Q[(size_t)(wave * 16 + l16) * NPIX + n0 + quad * 8];
    bf16x8 ak = *(const bf16x8*)&K[(size_t)(wave * 16 + l16) * NPIX + n0 + quad * 8];
    accQ = __builtin_amdgcn_mfma_f32_16x16x32_bf16(a, a, accQ, 0, 0, 0);
    accK = __builtin_amdgcn_mfma_f32_16x16x32_bf16(ak, ak, accK, 0, 0, 0);
    for (int j = 0; j < 4; j++) {
      bf16x8 bb = *(const bf16x8*)&K[(size_t)(j * 16 + l16) * NPIX + n0 + quad * 8];
      acc[j] = __builtin_amdgcn_mfma_f32_16x16x32_bf16(a, bb, acc[j], 0, 0, 0);
    }
  }
  for (int j = 0; j < 4; j++)
    for (int r = 0; r < 4; r++)
      Sf[wave * 16 + quad * 4 + r][j * 16 + l16] = acc[j][r];
  // diagonal of Q.Q^T / K.K^T: D row=quad*4+r, col=l16 -> diag where equal
  for (int r = 0; r < 4; r++)
    if (l16 == quad * 4 + r) {
      qq[wave * 16 + l16] = accQ[r];
      kk[wave * 16 + l16] = accK[r];
    }
  __syncthreads();
  if (tid < 64) invq[tid] = 1.f / fmaxf(sqrtf(qq[tid]), 1e-12f);
  else if (tid < 128) invk[tid - 64] = 1.f / fmaxf(sqrtf(kk[tid - 64]), 1e-12f);
  __syncthreads();

  // softmax over e: 256 threads = 64 rows x 4 segments of 16
  int row = tid & 63, seg = tid >> 6;
  float fq = temp[h] * invq[row];
  float v[16], pm = -1e30f;
  for (int i = 0; i < 16; i++) {
    v[i] = Sf[row][seg * 16 + i] * fq * invk[seg * 16 + i];
    pm = fmaxf(pm, v[i]);
  }
  redm[seg][row] = pm;
  __syncthreads();
  float m = fmaxf(fmaxf(redm[0][row], redm[1][row]),
                  fmaxf(redm[2][row], redm[3][row]));
  float ps = 0.f;
  for (int i = 0; i < 16; i++) { v[i] = __expf(v[i] - m); ps += v[i]; }
  reds[seg][row] = ps;
  __syncthreads();
  float inv = 1.f / (reds[0][row] + reds[1][row] + reds[2][row] + reds[3][row]);
  union { uint4 q4[2]; unsigned short s[16]; } u;
  for (int i = 0; i < 16; i++) u.s[i] = f2bf(v[i] * inv);
  unsigned short* Pp = P + ((size_t)bh * 64 + row) * 64 + seg * 16;
  *(uint4*)&Pp[0] = u.q4[0];
  *(uint4*)&Pp[8] = u.q4[1];
}

// ---------------- attn_o: O^T[n][d] = sum_e V^T[n][e] P[d][e] ----------------
// grid = bh*4 (n-quarters); register-prefetched V, LDS-staged coalesced stores.
__launch_bounds__(256)
__global__ void attn_o(const unsigned short* __restrict__ qkv,
                       const unsigned short* __restrict__ P,
                       unsigned short* __restrict__ aoT) {
  int blk = blockIdx.x;
  int nc = blk & 3, bh = blk >> 2;
  int b = bh >> 3, h = bh & 7;
  const unsigned short* V = qkv + ((size_t)b * QKV_M + 2 * CCH + h * 64) * NPIX;
  unsigned short* Ob = aoT + (size_t)b * NPIX * CCH + h * 64;
  int tid = threadIdx.x, lane = tid & 63, wave = tid >> 6;
  int quad = lane >> 4, l16 = lane & 15;

  __shared__ __align__(16) unsigned short Vt[4][16][72];
  __shared__ __align__(16) unsigned short Ot[4][16][72];

  // P fragments (B-operand: row d = j*16+l16, k = e)
  const unsigned short* Pb = P + (size_t)bh * 64 * 64;
  bf16x8 Pf[4][2];
  for (int j = 0; j < 4; j++)
    for (int ks = 0; ks < 2; ks++)
      Pf[j][ks] = *(const bf16x8*)&Pb[(j * 16 + l16) * 64 + ks * 32 + quad * 8];

  f32x4 zero = {0.f, 0.f, 0.f, 0.f};
  int e1 = lane >> 1, noff = (lane & 1) * 8;
  int nbase = nc * 256 + wave * 64;
  int orow = lane >> 3, ocol = (lane & 7) * 8;

  union { uint4 q; unsigned short s[8]; } g0, g1, c0, c1;
  g0.q = *(const uint4*)&V[(size_t)e1 * NPIX + nbase + noff];
  g1.q = *(const uint4*)&V[(size_t)(e1 + 32) * NPIX + nbase + noff];
#pragma unroll
  for (int nt = 0; nt < 4; nt++) {
    int n0 = nbase + nt * 16;
    c0 = g0; c1 = g1;
    if (nt < 3) {
      g0.q = *(const uint4*)&V[(size_t)e1 * NPIX + n0 + 16 + noff];
      g1.q = *(const uint4*)&V[(size_t)(e1 + 32) * NPIX + n0 + 16 + noff];
    }
    for (int jj = 0; jj < 8; jj++) {
      Vt[wave][noff + jj][e1]      = c0.s[jj];
      Vt[wave][noff + jj][e1 + 32] = c1.s[jj];
    }
    bf16x8 Af0 = *(const bf16x8*)&Vt[wave][l16][quad * 8];
    bf16x8 Af1 = *(const bf16x8*)&Vt[wave][l16][32 + quad * 8];
    f32x4 oacc[4];
    for (int j = 0; j < 4; j++) {
      oacc[j] = __builtin_amdgcn_mfma_f32_16x16x32_bf16(Af0, Pf[j][0], zero, 0, 0, 0);
      oacc[j] = __builtin_amdgcn_mfma_f32_16x16x32_bf16(Af1, Pf[j][1], oacc[j], 0, 0, 0);
    }
    for (int j = 0; j < 4; j++)
      for (int r = 0; r < 4; r++)
        Ot[wave][quad * 4 + r][j * 16 + l16] = f2bf(oacc[j][r]);
    uint4 o0 = *(const uint4*)&Ot[wave][orow][ocol];
    uint4 o1 = *(const uint4*)&Ot[wave][orow + 8][ocol];
    *(uint4*)&Ob[(size_t)(n0 + orow) * CCH + ocol] = o0;
    *(uint4*)&Ob[(size_t)(n0 + orow + 8) * CCH + ocol] = o1;
  }
}

// ---------------------------------------------------------------------------
extern "C" void kernel_launch(void* const* d_in, const int* in_sizes, int n_in,
                              void* d_out, int out_size, void* d_ws, size_t ws_size,
                              hipStream_t stream) {
  const float* x     = (const float*)d_in[0];
  const float* Wq    = (const float*)d_in[1];
  const float* Wk    = (const float*)d_in[2];
  const float* Wv    = (const float*)d_in[3];
  const float* dww   = (const float*)d_in[4];
  const float* gamma = (const float*)d_in[5];
  const float* beta  = (const float*)d_in[6];
  const float* temp  = (const float*)d_in[7];
  const float* Wp    = (const float*)d_in[8];
  const float* bp    = (const float*)d_in[9];
  float* out = (float*)d_out;

  char* ws = (char*)d_ws;
  unsigned short* wcat = (unsigned short*)ws;             // [1536,512] bf16
  unsigned short* wpb  = wcat + (size_t)QKV_M * CCH;      // [512,512] bf16
  float* s1 = (float*)(wpb + (size_t)CCH * CCH);
  float* s2 = s1 + CCH;
  unsigned short* Pbuf = (unsigned short*)(s2 + CCH);     // [B*H,64,64] bf16, 2MB
  char* dyn = (char*)(Pbuf + (size_t)BATCH * HEADS * 64 * 64);
  size_t fixed = (size_t)(dyn - ws);
  size_t per_b = ((size_t)NPIX * CCH + (size_t)QKV_M * NPIX) * 2;  // 4 MB/batch
  int BC = BATCH;
  while (BC > 1 && fixed + (size_t)BC * per_b > ws_size) BC >>= 1;
  unsigned short* xT  = (unsigned short*)dyn;                  // [BC,N,C]; reused as aoT
  unsigned short* qkv = xT + (size_t)BC * NPIX * CCH;          // [BC,1536,N]

  convert_w<<<CCH * CCH / 1024, 256, 0, stream>>>(Wq, Wk, Wv, Wp, wcat, wpb);
  hipMemsetAsync(s1, 0, 2 * CCH * sizeof(float), stream);
  dw_stats<<<dim3(CCH, BATCH), 256, 0, stream>>>(x, dww, s1, s2);

  for (int b0 = 0; b0 < BATCH; b0 += BC) {
    const float* xc = x + (size_t)b0 * CCH * NPIX;
    float* outc = out + (size_t)b0 * CCH * NPIX;
    transpose_f2b<<<dim3(NPIX / 32, CCH / 32, BC), dim3(32, 8), 0, stream>>>(
        xc, xT, CCH, NPIX);
    gemm_bt<false><<<dim3(NPIX / 256, QKV_M / 256, BC), 512, 0, stream>>>(
        wcat, xT, qkv, nullptr, QKV_M, NPIX, CCH);
    attn_s<<<BC * HEADS, 256, 0, stream>>>(qkv, temp, Pbuf);
    gate_apply<<<dim3(CCH, BC), 256, 0, stream>>>(xc, dww, s1, s2, gamma, beta, qkv);
    attn_o<<<BC * HEADS * 4, 256, 0, stream>>>(qkv, Pbuf, xT);  // aoT overwrites xT
    gemm_bt<true><<<dim3(NPIX / 256, CCH / 256, BC), 512, 0, stream>>>(
        wpb, xT, outc, bp, CCH, NPIX, CCH);
  }
}

// Round 4
// 328.662 us; speedup vs baseline: 1.0454x; 1.0123x over previous
//
#include <hip/hip_runtime.h>
#include <stdint.h>

#define BATCH 32
#define CCH   512
#define NPIX  1024
#define HEADS 8
#define QKV_M 1536   // q rows 0-511, k rows 512-1023, v rows 1024-1535

typedef short bf16x8 __attribute__((ext_vector_type(8)));
typedef float f32x4 __attribute__((ext_vector_type(4)));

__device__ inline float bf2f(unsigned short u) {
  union { float f; uint32_t i; } t; t.i = ((uint32_t)u) << 16; return t.f;
}
__device__ inline unsigned short f2bf(float f) {
  union { float f; uint32_t u; } t; t.f = f;
  uint32_t u = t.u;
  return (unsigned short)((u + 0x7FFFu + ((u >> 16) & 1u)) >> 16);
}

// async global->LDS, 16B per lane; LDS dest = wave-uniform base + lane*16
__device__ inline void gl_lds16(const unsigned short* g, unsigned short* l) {
  __builtin_amdgcn_global_load_lds(
      (const __attribute__((address_space(1))) uint32_t*)g,
      (__attribute__((address_space(3))) uint32_t*)l, 16, 0, 0);
}

// ---------------- weights fp32 -> bf16 (Wq|Wk|Wv concat, Wp separate) --------
__global__ void convert_w(const float* __restrict__ Wq, const float* __restrict__ Wk,
                          const float* __restrict__ Wv, const float* __restrict__ Wp,
                          unsigned short* __restrict__ wcat,
                          unsigned short* __restrict__ wpb) {
  int i = (blockIdx.x * 256 + threadIdx.x) * 4;   // over CCH*CCH = 262144
  union { ushort4 u4; unsigned short s[4]; } o;
  f32x4 a;
  a = *(const f32x4*)&Wq[i];
  for (int j = 0; j < 4; j++) o.s[j] = f2bf(a[j]);
  *(ushort4*)&wcat[i] = o.u4;
  a = *(const f32x4*)&Wk[i];
  for (int j = 0; j < 4; j++) o.s[j] = f2bf(a[j]);
  *(ushort4*)&wcat[CCH * CCH + i] = o.u4;
  a = *(const f32x4*)&Wv[i];
  for (int j = 0; j < 4; j++) o.s[j] = f2bf(a[j]);
  *(ushort4*)&wcat[2 * CCH * CCH + i] = o.u4;
  a = *(const f32x4*)&Wp[i];
  for (int j = 0; j < 4; j++) o.s[j] = f2bf(a[j]);
  *(ushort4*)&wpb[i] = o.u4;
}

// ---------------- transpose fp32 [b,R,Cc] -> bf16 [b,Cc,R] -------------------
__global__ void transpose_f2b(const float* __restrict__ in,
                              unsigned short* __restrict__ out, int R, int Cc) {
  __shared__ float tile[32][33];
  int b = blockIdx.z;
  int c0 = blockIdx.x * 32;
  int r0 = blockIdx.y * 32;
  const float* inb = in + (size_t)b * R * Cc;
  unsigned short* outb = out + (size_t)b * R * Cc;
  int tx = threadIdx.x, ty = threadIdx.y;
  for (int i = 0; i < 4; i++) {
    int r = ty + i * 8;
    tile[r][tx] = inb[(size_t)(r0 + r) * Cc + c0 + tx];
  }
  __syncthreads();
  for (int i = 0; i < 4; i++) {
    int r = ty + i * 8;
    outb[(size_t)(c0 + r) * R + r0 + tx] = f2bf(tile[tx][r]);
  }
}

// ---------------- gemm_bt: C[b][m][n] = sum_k A[m][k]*X[b][n][k] -------------
// 256x256 tile, BK=64, 512 threads = 8 waves (2 M x 4 N), mfma 16x16x32.
// 4 phases per K-tile keyed on C-QUADRANT with DISJOINT named fragment sets
// (WAR-free pipelining): ph0 loads af03+bf01 -> MFMA Q00; ph1 loads bf23
// (while Q00's MFMAs drain -- no shared regs) -> Q01; ph2 loads af47 -> Q10;
// ph3 stages tile t+2 into buf cur (fully drained after ph2) + counted
// s_waitcnt vmcnt(8) (tile t+1 landed, t+2's 8 stay in flight) -> Q11.
// 24 ds_read_b128 / wave / K-tile (non-redundant; quadrant reuse is in regs).
// Round-2 post-mortem: shared af[]/bfr[] arrays created WAR hazards that
// serialized ds_read behind the previous 32-MFMA cluster -> zero LDS/MFMA
// overlap (7800 cyc/K-tile vs ~3000 LDS-pipe floor). This is the m201
// template's quadrant ordering, which exists precisely to break that WAR.
template <bool OUT_F32>
__launch_bounds__(512, 1)
__global__ void gemm_bt(const unsigned short* __restrict__ A,
                        const unsigned short* __restrict__ X,
                        void* __restrict__ Cout,
                        const float* __restrict__ bias,
                        int M, int N, int K) {
  __shared__ __align__(16) unsigned short As[2][256 * 64];
  __shared__ __align__(16) unsigned short Bs[2][256 * 64];
  const int b  = blockIdx.z;
  const int m0 = blockIdx.y * 256;
  const int n0 = blockIdx.x * 256;
  const unsigned short* Xb = X + (size_t)b * N * K;
  const int tid  = threadIdx.x;
  const int lane = tid & 63;
  const int wave = tid >> 6;        // 0..7
  const int wm = wave >> 2;         // 0..1  (M half: 128 rows each)
  const int wn = wave & 3;          // 0..3  (N quarter: 64 cols each)
  const int quad = lane >> 4, l16 = lane & 15;

  f32x4 acc[8][4];
  const f32x4 zero = {0.f, 0.f, 0.f, 0.f};
#pragma unroll
  for (int i = 0; i < 8; i++)
#pragma unroll
    for (int j = 0; j < 4; j++) acc[i][j] = zero;

  // staging geometry: wave w covers rows [w*32, w*32+32), 4 loads of 8 rows
  // per matrix. lane -> row += lane>>3; fetched k-chunk = (lane&7)^(lane>>3)
  // (XOR swizzle; still one 128B segment per 8-lane row-group -> coalesced).
  const int r8  = lane >> 3;
  const int swk = ((lane & 7) ^ r8) * 8;
  const unsigned short* Ag = A  + (size_t)(m0 + wave * 32 + r8) * K + swk;
  const unsigned short* Xg = Xb + (size_t)(n0 + wave * 32 + r8) * K + swk;

  const int NT = K >> 6;            // K-tiles of 64

  auto stage = [&](int kt, int bsel) {
    unsigned short* Al = &As[bsel][wave * 32 * 64];
    unsigned short* Bl = &Bs[bsel][wave * 32 * 64];
    const unsigned short* Agk = Ag + kt * 64;
    const unsigned short* Xgk = Xg + kt * 64;
#pragma unroll
    for (int i = 0; i < 4; ++i) {
      gl_lds16(Agk + (size_t)i * 8 * K, Al + i * 8 * 64);
      gl_lds16(Xgk + (size_t)i * 8 * K, Bl + i * 8 * 64);
    }
  };

  // prologue: tiles 0 and 1 in flight; wait tile 0 (8 newest stay in flight)
  stage(0, 0);
  if (NT > 1) stage(1, 1);
  asm volatile("s_waitcnt vmcnt(8)" ::: "memory");
  __builtin_amdgcn_s_barrier();

  for (int t = 0; t < NT; ++t) {
    const int cur = t & 1;
    const unsigned short* Asl = As[cur];
    const unsigned short* Bsl = Bs[cur];
    bf16x8 af03[4][2], af47[4][2], bf01[2][2], bf23[2][2];

    // ---- phase 0: load af03 (8) + bf01 (4); MFMA Q00 (m0-3 x n0-1) ----
#pragma unroll
    for (int ii = 0; ii < 4; ++ii)
#pragma unroll
      for (int ks = 0; ks < 2; ++ks) {
        const int ch = ((ks * 4 + quad) ^ (l16 & 7)) * 8;
        af03[ii][ks] = *(const bf16x8*)&Asl[(wm * 128 + ii * 16 + l16) * 64 + ch];
      }
#pragma unroll
    for (int jj = 0; jj < 2; ++jj)
#pragma unroll
      for (int ks = 0; ks < 2; ++ks) {
        const int ch = ((ks * 4 + quad) ^ (l16 & 7)) * 8;
        bf01[jj][ks] = *(const bf16x8*)&Bsl[(wn * 64 + jj * 16 + l16) * 64 + ch];
      }
    __builtin_amdgcn_s_barrier();
    asm volatile("s_waitcnt lgkmcnt(0)" ::: "memory");
    __builtin_amdgcn_sched_barrier(0);
    __builtin_amdgcn_s_setprio(1);
#pragma unroll
    for (int ks = 0; ks < 2; ++ks)
#pragma unroll
      for (int ii = 0; ii < 4; ++ii)
#pragma unroll
        for (int jj = 0; jj < 2; ++jj)
          acc[ii][jj] = __builtin_amdgcn_mfma_f32_16x16x32_bf16(
              af03[ii][ks], bf01[jj][ks], acc[ii][jj], 0, 0, 0);
    __builtin_amdgcn_s_setprio(0);
    __builtin_amdgcn_s_barrier();

    // ---- phase 1: load bf23 (4) [Q00 drains -- disjoint regs]; Q01 ----
#pragma unroll
    for (int jj = 0; jj < 2; ++jj)
#pragma unroll
      for (int ks = 0; ks < 2; ++ks) {
        const int ch = ((ks * 4 + quad) ^ (l16 & 7)) * 8;
        bf23[jj][ks] = *(const bf16x8*)&Bsl[(wn * 64 + (2 + jj) * 16 + l16) * 64 + ch];
      }
    __builtin_amdgcn_s_barrier();
    asm volatile("s_waitcnt lgkmcnt(0)" ::: "memory");
    __builtin_amdgcn_sched_barrier(0);
    __builtin_amdgcn_s_setprio(1);
#pragma unroll
    for (int ks = 0; ks < 2; ++ks)
#pragma unroll
      for (int ii = 0; ii < 4; ++ii)
#pragma unroll
        for (int jj = 0; jj < 2; ++jj)
          acc[ii][2 + jj] = __builtin_amdgcn_mfma_f32_16x16x32_bf16(
              af03[ii][ks], bf23[jj][ks], acc[ii][2 + jj], 0, 0, 0);
    __builtin_amdgcn_s_setprio(0);
    __builtin_amdgcn_s_barrier();

    // ---- phase 2: load af47 (8) [Q01 drains]; Q10 (m4-7 x n0-1) ----
#pragma unroll
    for (int ii = 0; ii < 4; ++ii)
#pragma unroll
      for (int ks = 0; ks < 2; ++ks) {
        const int ch = ((ks * 4 + quad) ^ (l16 & 7)) * 8;
        af47[ii][ks] =
            *(const bf16x8*)&Asl[(wm * 128 + (4 + ii) * 16 + l16) * 64 + ch];
      }
    __builtin_amdgcn_s_barrier();
    asm volatile("s_waitcnt lgkmcnt(0)" ::: "memory");
    __builtin_amdgcn_sched_barrier(0);
    __builtin_amdgcn_s_setprio(1);
#pragma unroll
    for (int ks = 0; ks < 2; ++ks)
#pragma unroll
      for (int ii = 0; ii < 4; ++ii)
#pragma unroll
        for (int jj = 0; jj < 2; ++jj)
          acc[4 + ii][jj] = __builtin_amdgcn_mfma_f32_16x16x32_bf16(
              af47[ii][ks], bf01[jj][ks], acc[4 + ii][jj], 0, 0, 0);
    __builtin_amdgcn_s_setprio(0);
    __builtin_amdgcn_s_barrier();

    // ---- phase 3: stage tile t+2 into buf cur (drained after ph2);
    //      counted vmcnt(8) = tile t+1 landed; Q11 (m4-7 x n2-3) ----
    if (t + 2 < NT) {
      stage(t + 2, cur);
      asm volatile("s_waitcnt vmcnt(8)" ::: "memory");
    } else if (t + 1 < NT) {
      asm volatile("s_waitcnt vmcnt(0)" ::: "memory");
    }
    __builtin_amdgcn_s_barrier();
    __builtin_amdgcn_s_setprio(1);
#pragma unroll
    for (int ks = 0; ks < 2; ++ks)
#pragma unroll
      for (int ii = 0; ii < 4; ++ii)
#pragma unroll
        for (int jj = 0; jj < 2; ++jj)
          acc[4 + ii][2 + jj] = __builtin_amdgcn_mfma_f32_16x16x32_bf16(
              af47[ii][ks], bf23[jj][ks], acc[4 + ii][2 + jj], 0, 0, 0);
    __builtin_amdgcn_s_setprio(0);
    __builtin_amdgcn_s_barrier();
  }

  // C/D layout: row = quad*4+reg, col = l16
#pragma unroll
  for (int i = 0; i < 8; ++i) {
#pragma unroll
    for (int r = 0; r < 4; ++r) {
      const int gm = m0 + wm * 128 + i * 16 + quad * 4 + r;
      if constexpr (OUT_F32) {
        const float bv = bias[gm];
        float* Co = (float*)Cout + (size_t)b * M * N + (size_t)gm * N +
                    n0 + wn * 64 + l16;
#pragma unroll
        for (int j = 0; j < 4; ++j) Co[j * 16] = acc[i][j][r] + bv;
      } else {
        unsigned short* Co = (unsigned short*)Cout + (size_t)b * M * N +
                             (size_t)gm * N + n0 + wn * 64 + l16;
#pragma unroll
        for (int j = 0; j < 4; ++j) Co[j * 16] = f2bf(acc[i][j][r]);
      }
    }
  }
}

// ---------------- depthwise 3x3 per-channel stats (sum, sumsq) ---------------
__global__ void dw_stats(const float* __restrict__ x,
                         const float* __restrict__ wgt,
                         float* __restrict__ s1, float* __restrict__ s2) {
  int c = blockIdx.x, b = blockIdx.y;
  __shared__ __align__(16) float plane[NPIX];
  const float* xp = x + ((size_t)b * CCH + c) * NPIX;
  *(f32x4*)&plane[threadIdx.x * 4] = *(const f32x4*)&xp[threadIdx.x * 4];
  __syncthreads();
  float w[9];
  for (int i = 0; i < 9; i++) w[i] = wgt[c * 9 + i];
  float a1 = 0.f, a2 = 0.f;
  for (int pi = 0; pi < 4; pi++) {
    int p = threadIdx.x + pi * 256;
    int h = p >> 5, wc = p & 31;
    float v = 0.f;
    for (int dh = -1; dh <= 1; dh++)
      for (int dw = -1; dw <= 1; dw++) {
        int hh = h + dh, ww = wc + dw;
        if (hh >= 0 && hh < 32 && ww >= 0 && ww < 32)
          v += w[(dh + 1) * 3 + dw + 1] * plane[hh * 32 + ww];
      }
    a1 += v; a2 += v * v;
  }
  for (int off = 32; off > 0; off >>= 1) {
    a1 += __shfl_down(a1, off);
    a2 += __shfl_down(a2, off);
  }
  __shared__ float r1[4], r2[4];
  int wv = threadIdx.x >> 6;
  if ((threadIdx.x & 63) == 0) { r1[wv] = a1; r2[wv] = a2; }
  __syncthreads();
  if (threadIdx.x == 0) {
    atomicAdd(&s1[c], r1[0] + r1[1] + r1[2] + r1[3]);
    atomicAdd(&s2[c], r2[0] + r2[1] + r2[2] + r2[3]);
  }
}

// ---------------- gate: v (rows 1024..1535 of qkv) *= SiLU(BN(conv(x))) ------
__global__ void gate_apply(const float* __restrict__ x,
                           const float* __restrict__ wgt,
                           const float* __restrict__ s1, const float* __restrict__ s2,
                           const float* __restrict__ gamma,
                           const float* __restrict__ beta,
                           unsigned short* __restrict__ qkv) {
  int c = blockIdx.x, b = blockIdx.y;
  __shared__ __align__(16) float plane[NPIX];
  const float* xp = x + ((size_t)b * CCH + c) * NPIX;
  unsigned short* vp = qkv + ((size_t)b * QKV_M + 2 * CCH + c) * NPIX;
  *(f32x4*)&plane[threadIdx.x * 4] = *(const f32x4*)&xp[threadIdx.x * 4];
  __syncthreads();
  float w[9];
  for (int i = 0; i < 9; i++) w[i] = wgt[c * 9 + i];
  const float invn = 1.f / 32768.f;
  float mean = s1[c] * invn;
  float var = fmaxf(s2[c] * invn - mean * mean, 0.f);
  float rstd = rsqrtf(var + 1e-5f);
  float ga = gamma[c], be = beta[c];
  for (int pi = 0; pi < 4; pi++) {
    int p = threadIdx.x + pi * 256;
    int h = p >> 5, wc = p & 31;
    float val = 0.f;
    for (int dh = -1; dh <= 1; dh++)
      for (int dw = -1; dw <= 1; dw++) {
        int hh = h + dh, ww = wc + dw;
        if (hh >= 0 && hh < 32 && ww >= 0 && ww < 32)
          val += w[(dh + 1) * 3 + dw + 1] * plane[hh * 32 + ww];
      }
    float g = (val - mean) * rstd * ga + be;
    float sg = g / (1.f + __expf(-g));      // SiLU
    vp[p] = f2bf(bf2f(vp[p]) * sg);
  }
}

// ---------------- attn_s: S=QK^T (+ fused l2norm via QQ^T/KK^T diag),
//                  softmax -> P [bh][64][64] bf16 -------------------------------
__launch_bounds__(256)
__global__ void attn_s(const unsigned short* __restrict__ qkv,
                       const float* __restrict__ temp,
                       unsigned short* __restrict__ P) {
  int bh = blockIdx.x;
  int b = bh >> 3, h = bh & 7;
  const unsigned short* Q = qkv + ((size_t)b * QKV_M + h * 64) * NPIX;
  const unsigned short* K = Q + (size_t)CCH * NPIX;
  int tid = threadIdx.x, lane = tid & 63, wave = tid >> 6;
  int quad = lane >> 4, l16 = lane & 15;

  __shared__ __align__(16) float Sf[64][65];
  __shared__ float qq[64], kk[64], invq[64], invk[64];
  __shared__ float redm[4][64], reds[4][64];

  f32x4 zero = {0.f, 0.f, 0.f, 0.f};
  f32x4 acc[4], accQ = zero, accK = zero;
  for (int j = 0; j < 4; j++) acc[j] = zero;
  for (int n0 = 0; n0 < NPIX; n0 += 32) {
    bf16x8 a  = *(const bf16x8*)&Q[(size_t)(wave * 16 + l16) * NPIX + n0 + quad * 8];
    bf16x8 ak = *(const bf16x8*)&K[(size_t)(wave * 16 + l16) * NPIX + n0 + quad * 8];
    accQ = __builtin_amdgcn_mfma_f32_16x16x32_bf16(a, a, accQ, 0, 0, 0);
    accK = __builtin_amdgcn_mfma_f32_16x16x32_bf16(ak, ak, accK, 0, 0, 0);
    for (int j = 0; j < 4; j++) {
      bf16x8 bb = *(const bf16x8*)&K[(size_t)(j * 16 + l16) * NPIX + n0 + quad * 8];
      acc[j] = __builtin_amdgcn_mfma_f32_16x16x32_bf16(a, bb, acc[j], 0, 0, 0);
    }
  }
  for (int j = 0; j < 4; j++)
    for (int r = 0; r < 4; r++)
      Sf[wave * 16 + quad * 4 + r][j * 16 + l16] = acc[j][r];
  // diagonal of Q.Q^T / K.K^T: D row=quad*4+r, col=l16 -> diag where equal
  for (int r = 0; r < 4; r++)
    if (l16 == quad * 4 + r) {
      qq[wave * 16 + l16] = accQ[r];
      kk[wave * 16 + l16] = accK[r];
    }
  __syncthreads();
  if (tid < 64) invq[tid] = 1.f / fmaxf(sqrtf(qq[tid]), 1e-12f);
  else if (tid < 128) invk[tid - 64] = 1.f / fmaxf(sqrtf(kk[tid - 64]), 1e-12f);
  __syncthreads();

  // softmax over e: 256 threads = 64 rows x 4 segments of 16
  int row = tid & 63, seg = tid >> 6;
  float fq = temp[h] * invq[row];
  float v[16], pm = -1e30f;
  for (int i = 0; i < 16; i++) {
    v[i] = Sf[row][seg * 16 + i] * fq * invk[seg * 16 + i];
    pm = fmaxf(pm, v[i]);
  }
  redm[seg][row] = pm;
  __syncthreads();
  float m = fmaxf(fmaxf(redm[0][row], redm[1][row]),
                  fmaxf(redm[2][row], redm[3][row]));
  float ps = 0.f;
  for (int i = 0; i < 16; i++) { v[i] = __expf(v[i] - m); ps += v[i]; }
  reds[seg][row] = ps;
  __syncthreads();
  float inv = 1.f / (reds[0][row] + reds[1][row] + reds[2][row] + reds[3][row]);
  union { uint4 q4[2]; unsigned short s[16]; } u;
  for (int i = 0; i < 16; i++) u.s[i] = f2bf(v[i] * inv);
  unsigned short* Pp = P + ((size_t)bh * 64 + row) * 64 + seg * 16;
  *(uint4*)&Pp[0] = u.q4[0];
  *(uint4*)&Pp[8] = u.q4[1];
}

// ---------------- attn_o: O^T[n][d] = sum_e V^T[n][e] P[d][e] ----------------
// grid = bh*4 (n-quarters); register-prefetched V, LDS-staged coalesced stores.
__launch_bounds__(256)
__global__ void attn_o(const unsigned short* __restrict__ qkv,
                       const unsigned short* __restrict__ P,
                       unsigned short* __restrict__ aoT) {
  int blk = blockIdx.x;
  int nc = blk & 3, bh = blk >> 2;
  int b = bh >> 3, h = bh & 7;
  const unsigned short* V = qkv + ((size_t)b * QKV_M + 2 * CCH + h * 64) * NPIX;
  unsigned short* Ob = aoT + (size_t)b * NPIX * CCH + h * 64;
  int tid = threadIdx.x, lane = tid & 63, wave = tid >> 6;
  int quad = lane >> 4, l16 = lane & 15;

  __shared__ __align__(16) unsigned short Vt[4][16][72];
  __shared__ __align__(16) unsigned short Ot[4][16][72];

  // P fragments (B-operand: row d = j*16+l16, k = e)
  const unsigned short* Pb = P + (size_t)bh * 64 * 64;
  bf16x8 Pf[4][2];
  for (int j = 0; j < 4; j++)
    for (int ks = 0; ks < 2; ks++)
      Pf[j][ks] = *(const bf16x8*)&Pb[(j * 16 + l16) * 64 + ks * 32 + quad * 8];

  f32x4 zero = {0.f, 0.f, 0.f, 0.f};
  int e1 = lane >> 1, noff = (lane & 1) * 8;
  int nbase = nc * 256 + wave * 64;
  int orow = lane >> 3, ocol = (lane & 7) * 8;

  union { uint4 q; unsigned short s[8]; } g0, g1, c0, c1;
  g0.q = *(const uint4*)&V[(size_t)e1 * NPIX + nbase + noff];
  g1.q = *(const uint4*)&V[(size_t)(e1 + 32) * NPIX + nbase + noff];
#pragma unroll
  for (int nt = 0; nt < 4; nt++) {
    int n0 = nbase + nt * 16;
    c0 = g0; c1 = g1;
    if (nt < 3) {
      g0.q = *(const uint4*)&V[(size_t)e1 * NPIX + n0 + 16 + noff];
      g1.q = *(const uint4*)&V[(size_t)(e1 + 32) * NPIX + n0 + 16 + noff];
    }
    for (int jj = 0; jj < 8; jj++) {
      Vt[wave][noff + jj][e1]      = c0.s[jj];
      Vt[wave][noff + jj][e1 + 32] = c1.s[jj];
    }
    bf16x8 Af0 = *(const bf16x8*)&Vt[wave][l16][quad * 8];
    bf16x8 Af1 = *(const bf16x8*)&Vt[wave][l16][32 + quad * 8];
    f32x4 oacc[4];
    for (int j = 0; j < 4; j++) {
      oacc[j] = __builtin_amdgcn_mfma_f32_16x16x32_bf16(Af0, Pf[j][0], zero, 0, 0, 0);
      oacc[j] = __builtin_amdgcn_mfma_f32_16x16x32_bf16(Af1, Pf[j][1], oacc[j], 0, 0, 0);
    }
    for (int j = 0; j < 4; j++)
      for (int r = 0; r < 4; r++)
        Ot[wave][quad * 4 + r][j * 16 + l16] = f2bf(oacc[j][r]);
    uint4 o0 = *(const uint4*)&Ot[wave][orow][ocol];
    uint4 o1 = *(const uint4*)&Ot[wave][orow + 8][ocol];
    *(uint4*)&Ob[(size_t)(n0 + orow) * CCH + ocol] = o0;
    *(uint4*)&Ob[(size_t)(n0 + orow + 8) * CCH + ocol] = o1;
  }
}

// ---------------------------------------------------------------------------
extern "C" void kernel_launch(void* const* d_in, const int* in_sizes, int n_in,
                              void* d_out, int out_size, void* d_ws, size_t ws_size,
                              hipStream_t stream) {
  const float* x     = (const float*)d_in[0];
  const float* Wq    = (const float*)d_in[1];
  const float* Wk    = (const float*)d_in[2];
  const float* Wv    = (const float*)d_in[3];
  const float* dww   = (const float*)d_in[4];
  const float* gamma = (const float*)d_in[5];
  const float* beta  = (const float*)d_in[6];
  const float* temp  = (const float*)d_in[7];
  const float* Wp    = (const float*)d_in[8];
  const float* bp    = (const float*)d_in[9];
  float* out = (float*)d_out;

  char* ws = (char*)d_ws;
  unsigned short* wcat = (unsigned short*)ws;             // [1536,512] bf16
  unsigned short* wpb  = wcat + (size_t)QKV_M * CCH;      // [512,512] bf16
  float* s1 = (float*)(wpb + (size_t)CCH * CCH);
  float* s2 = s1 + CCH;
  unsigned short* Pbuf = (unsigned short*)(s2 + CCH);     // [B*H,64,64] bf16, 2MB
  char* dyn = (char*)(Pbuf + (size_t)BATCH * HEADS * 64 * 64);
  size_t fixed = (size_t)(dyn - ws);
  size_t per_b = ((size_t)NPIX * CCH + (size_t)QKV_M * NPIX) * 2;  // 4 MB/batch
  int BC = BATCH;
  while (BC > 1 && fixed + (size_t)BC * per_b > ws_size) BC >>= 1;
  unsigned short* xT  = (unsigned short*)dyn;                  // [BC,N,C]; reused as aoT
  unsigned short* qkv = xT + (size_t)BC * NPIX * CCH;          // [BC,1536,N]

  convert_w<<<CCH * CCH / 1024, 256, 0, stream>>>(Wq, Wk, Wv, Wp, wcat, wpb);
  hipMemsetAsync(s1, 0, 2 * CCH * sizeof(float), stream);
  dw_stats<<<dim3(CCH, BATCH), 256, 0, stream>>>(x, dww, s1, s2);

  for (int b0 = 0; b0 < BATCH; b0 += BC) {
    const float* xc = x + (size_t)b0 * CCH * NPIX;
    float* outc = out + (size_t)b0 * CCH * NPIX;
    transpose_f2b<<<dim3(NPIX / 32, CCH / 32, BC), dim3(32, 8), 0, stream>>>(
        xc, xT, CCH, NPIX);
    gemm_bt<false><<<dim3(NPIX / 256, QKV_M / 256, BC), 512, 0, stream>>>(
        wcat, xT, qkv, nullptr, QKV_M, NPIX, CCH);
    attn_s<<<BC * HEADS, 256, 0, stream>>>(qkv, temp, Pbuf);
    gate_apply<<<dim3(CCH, BC), 256, 0, stream>>>(xc, dww, s1, s2, gamma, beta, qkv);
    attn_o<<<BC * HEADS * 4, 256, 0, stream>>>(qkv, Pbuf, xT);  // aoT overwrites xT
    gemm_bt<true><<<dim3(NPIX / 256, CCH / 256, BC), 512, 0, stream>>>(
        wpb, xT, outc, bp, CCH, NPIX, CCH);
  }
}

// Round 5
// 323.294 us; speedup vs baseline: 1.0628x; 1.0166x over previous
//
#include <hip/hip_runtime.h>
#include <stdint.h>

#define BATCH 32
#define CCH   512
#define NPIX  1024
#define HEADS 8
#define QKV_M 1536   // q rows 0-511, k rows 512-1023, v rows 1024-1535

typedef short bf16x8 __attribute__((ext_vector_type(8)));
typedef float f32x4 __attribute__((ext_vector_type(4)));

__device__ inline float bf2f(unsigned short u) {
  union { float f; uint32_t i; } t; t.i = ((uint32_t)u) << 16; return t.f;
}
__device__ inline unsigned short f2bf(float f) {
  union { float f; uint32_t u; } t; t.f = f;
  uint32_t u = t.u;
  return (unsigned short)((u + 0x7FFFu + ((u >> 16) & 1u)) >> 16);
}

// async global->LDS, 16B per lane; LDS dest = wave-uniform base + lane*16
__device__ inline void gl_lds16(const unsigned short* g, unsigned short* l) {
  __builtin_amdgcn_global_load_lds(
      (const __attribute__((address_space(1))) uint32_t*)g,
      (__attribute__((address_space(3))) uint32_t*)l, 16, 0, 0);
}

// ---------------- weights fp32 -> bf16 (Wq|Wk|Wv concat, Wp separate) --------
__global__ void convert_w(const float* __restrict__ Wq, const float* __restrict__ Wk,
                          const float* __restrict__ Wv, const float* __restrict__ Wp,
                          unsigned short* __restrict__ wcat,
                          unsigned short* __restrict__ wpb) {
  int i = (blockIdx.x * 256 + threadIdx.x) * 4;   // over CCH*CCH = 262144
  union { ushort4 u4; unsigned short s[4]; } o;
  f32x4 a;
  a = *(const f32x4*)&Wq[i];
  for (int j = 0; j < 4; j++) o.s[j] = f2bf(a[j]);
  *(ushort4*)&wcat[i] = o.u4;
  a = *(const f32x4*)&Wk[i];
  for (int j = 0; j < 4; j++) o.s[j] = f2bf(a[j]);
  *(ushort4*)&wcat[CCH * CCH + i] = o.u4;
  a = *(const f32x4*)&Wv[i];
  for (int j = 0; j < 4; j++) o.s[j] = f2bf(a[j]);
  *(ushort4*)&wcat[2 * CCH * CCH + i] = o.u4;
  a = *(const f32x4*)&Wp[i];
  for (int j = 0; j < 4; j++) o.s[j] = f2bf(a[j]);
  *(ushort4*)&wpb[i] = o.u4;
}

// ---------------- transpose fp32 [b,R,Cc] -> bf16 [b,Cc,R] -------------------
__global__ void transpose_f2b(const float* __restrict__ in,
                              unsigned short* __restrict__ out, int R, int Cc) {
  __shared__ float tile[32][33];
  int b = blockIdx.z;
  int c0 = blockIdx.x * 32;
  int r0 = blockIdx.y * 32;
  const float* inb = in + (size_t)b * R * Cc;
  unsigned short* outb = out + (size_t)b * R * Cc;
  int tx = threadIdx.x, ty = threadIdx.y;
  for (int i = 0; i < 4; i++) {
    int r = ty + i * 8;
    tile[r][tx] = inb[(size_t)(r0 + r) * Cc + c0 + tx];
  }
  __syncthreads();
  for (int i = 0; i < 4; i++) {
    int r = ty + i * 8;
    outb[(size_t)(c0 + r) * R + r0 + tx] = f2bf(tile[tx][r]);
  }
}

// ---------------- gemm_bt: C[b][m][n] = sum_k A[m][k]*X[b][n][k] -------------
// 256x256 tile, BK=64, 512 threads = 8 waves (2 M x 4 N), mfma 16x16x32.
// Double-buffered LDS (128 KiB), gl_lds16 staging with XOR chunk swizzle
// (conflict-free ds_read_b128, measured SQ_LDS_BANK_CONFLICT==0).
// COMPILER-SCHEDULED body (round-4 post-mortem): rounds 1-3 pinned every
// phase with asm lgkmcnt(0)+sched_barrier(0)+2 barriers; MfmaUtil stuck at
// 23-27% across three different phase orders. m141 precedent: order-pinning
// regresses; m97 asm shows compiler emits fine-grained lgkmcnt(4/3/1/0)
// on its own for non-asm ds_reads. So: per K-tile, read all 24 fragments +
// 64 MFMA in ONE unpinned region (compiler interleaves), then exactly two
// barriers: [reads consumed] -> stage(t+2,cur) -> counted vmcnt(8) ->
// [tile t+1 published]. Counted vmcnt keeps next tile's 8 loads in flight
// across the barrier (T4); no drain-to-0 in the main loop.
template <bool OUT_F32>
__launch_bounds__(512, 2)   // waves/EU=2 caps VGPR at 256 (8-wave block needs 2/SIMD)
__global__ void gemm_bt(const unsigned short* __restrict__ A,
                        const unsigned short* __restrict__ X,
                        void* __restrict__ Cout,
                        const float* __restrict__ bias,
                        int M, int N, int K) {
  __shared__ __align__(16) unsigned short As[2][256 * 64];
  __shared__ __align__(16) unsigned short Bs[2][256 * 64];
  const int b  = blockIdx.z;
  const int m0 = blockIdx.y * 256;
  const int n0 = blockIdx.x * 256;
  const unsigned short* Xb = X + (size_t)b * N * K;
  const int tid  = threadIdx.x;
  const int lane = tid & 63;
  const int wave = tid >> 6;        // 0..7
  const int wm = wave >> 2;         // 0..1  (M half: 128 rows each)
  const int wn = wave & 3;          // 0..3  (N quarter: 64 cols each)
  const int quad = lane >> 4, l16 = lane & 15;

  f32x4 acc[8][4];
  const f32x4 zero = {0.f, 0.f, 0.f, 0.f};
#pragma unroll
  for (int i = 0; i < 8; i++)
#pragma unroll
    for (int j = 0; j < 4; j++) acc[i][j] = zero;

  // staging geometry: wave w covers rows [w*32, w*32+32), 4 loads of 8 rows
  // per matrix. lane -> row += lane>>3; fetched k-chunk = (lane&7)^(lane>>3)
  // (XOR swizzle; still one 128B segment per 8-lane row-group -> coalesced).
  const int r8  = lane >> 3;
  const int swk = ((lane & 7) ^ r8) * 8;
  const unsigned short* Ag = A  + (size_t)(m0 + wave * 32 + r8) * K + swk;
  const unsigned short* Xg = Xb + (size_t)(n0 + wave * 32 + r8) * K + swk;

  const int NT = K >> 6;            // K-tiles of 64

  auto stage = [&](int kt, int bsel) {
    unsigned short* Al = &As[bsel][wave * 32 * 64];
    unsigned short* Bl = &Bs[bsel][wave * 32 * 64];
    const unsigned short* Agk = Ag + kt * 64;
    const unsigned short* Xgk = Xg + kt * 64;
#pragma unroll
    for (int i = 0; i < 4; ++i) {
      gl_lds16(Agk + (size_t)i * 8 * K, Al + i * 8 * 64);
      gl_lds16(Xgk + (size_t)i * 8 * K, Bl + i * 8 * 64);
    }
  };

  // prologue: tiles 0 and 1 in flight; wait tile 0 (tile 1's 8 stay in flight)
  stage(0, 0);
  if (NT > 1) stage(1, 1);
  asm volatile("s_waitcnt vmcnt(8)" ::: "memory");
  __builtin_amdgcn_s_barrier();

  for (int t = 0; t < NT; ++t) {
    const int cur = t & 1;
    const unsigned short* Asl = As[cur];
    const unsigned short* Bsl = Bs[cur];

    // -------- unpinned compute region: 24 ds_read_b128 + 64 MFMA --------
    // (compiler inserts fine-grained lgkmcnt and interleaves reads/MFMAs)
    {
      // fragment read: logical chunk (ks*4+quad) lives at physical ^(l16&7)
      bf16x8 a0[8], b0[4];
      const int ch0 = ((0 * 4 + quad) ^ (l16 & 7)) * 8;
#pragma unroll
      for (int ii = 0; ii < 8; ++ii)
        a0[ii] = *(const bf16x8*)&Asl[(wm * 128 + ii * 16 + l16) * 64 + ch0];
#pragma unroll
      for (int jj = 0; jj < 4; ++jj)
        b0[jj] = *(const bf16x8*)&Bsl[(wn * 64 + jj * 16 + l16) * 64 + ch0];

      bf16x8 a1[8], b1[4];
      const int ch1 = ((1 * 4 + quad) ^ (l16 & 7)) * 8;
#pragma unroll
      for (int ii = 0; ii < 8; ++ii)
        a1[ii] = *(const bf16x8*)&Asl[(wm * 128 + ii * 16 + l16) * 64 + ch1];
#pragma unroll
      for (int jj = 0; jj < 4; ++jj)
        b1[jj] = *(const bf16x8*)&Bsl[(wn * 64 + jj * 16 + l16) * 64 + ch1];

#pragma unroll
      for (int ii = 0; ii < 8; ++ii)
#pragma unroll
        for (int jj = 0; jj < 4; ++jj)
          acc[ii][jj] = __builtin_amdgcn_mfma_f32_16x16x32_bf16(
              a0[ii], b0[jj], acc[ii][jj], 0, 0, 0);
#pragma unroll
      for (int ii = 0; ii < 8; ++ii)
#pragma unroll
        for (int jj = 0; jj < 4; ++jj)
          acc[ii][jj] = __builtin_amdgcn_mfma_f32_16x16x32_bf16(
              a1[ii], b1[jj], acc[ii][jj], 0, 0, 0);
    }

    // -------- sync skeleton: 2 barriers + counted vmcnt per K-tile --------
    __builtin_amdgcn_s_barrier();      // all waves consumed buf cur
    if (t + 2 < NT) {
      stage(t + 2, cur);               // overwrite drained buffer
      asm volatile("s_waitcnt vmcnt(8)" ::: "memory");  // tile t+1 landed
    } else if (t + 1 < NT) {
      asm volatile("s_waitcnt vmcnt(0)" ::: "memory");  // final drain
    }
    __builtin_amdgcn_s_barrier();      // publish tile t+1
  }

  // C/D layout: row = quad*4+reg, col = l16
#pragma unroll
  for (int i = 0; i < 8; ++i) {
#pragma unroll
    for (int r = 0; r < 4; ++r) {
      const int gm = m0 + wm * 128 + i * 16 + quad * 4 + r;
      if constexpr (OUT_F32) {
        const float bv = bias[gm];
        float* Co = (float*)Cout + (size_t)b * M * N + (size_t)gm * N +
                    n0 + wn * 64 + l16;
#pragma unroll
        for (int j = 0; j < 4; ++j) Co[j * 16] = acc[i][j][r] + bv;
      } else {
        unsigned short* Co = (unsigned short*)Cout + (size_t)b * M * N +
                             (size_t)gm * N + n0 + wn * 64 + l16;
#pragma unroll
        for (int j = 0; j < 4; ++j) Co[j * 16] = f2bf(acc[i][j][r]);
      }
    }
  }
}

// ---------------- depthwise 3x3 per-channel stats (sum, sumsq) ---------------
__global__ void dw_stats(const float* __restrict__ x,
                         const float* __restrict__ wgt,
                         float* __restrict__ s1, float* __restrict__ s2) {
  int c = blockIdx.x, b = blockIdx.y;
  __shared__ __align__(16) float plane[NPIX];
  const float* xp = x + ((size_t)b * CCH + c) * NPIX;
  *(f32x4*)&plane[threadIdx.x * 4] = *(const f32x4*)&xp[threadIdx.x * 4];
  __syncthreads();
  float w[9];
  for (int i = 0; i < 9; i++) w[i] = wgt[c * 9 + i];
  float a1 = 0.f, a2 = 0.f;
  for (int pi = 0; pi < 4; pi++) {
    int p = threadIdx.x + pi * 256;
    int h = p >> 5, wc = p & 31;
    float v = 0.f;
    for (int dh = -1; dh <= 1; dh++)
      for (int dw = -1; dw <= 1; dw++) {
        int hh = h + dh, ww = wc + dw;
        if (hh >= 0 && hh < 32 && ww >= 0 && ww < 32)
          v += w[(dh + 1) * 3 + dw + 1] * plane[hh * 32 + ww];
      }
    a1 += v; a2 += v * v;
  }
  for (int off = 32; off > 0; off >>= 1) {
    a1 += __shfl_down(a1, off);
    a2 += __shfl_down(a2, off);
  }
  __shared__ float r1[4], r2[4];
  int wv = threadIdx.x >> 6;
  if ((threadIdx.x & 63) == 0) { r1[wv] = a1; r2[wv] = a2; }
  __syncthreads();
  if (threadIdx.x == 0) {
    atomicAdd(&s1[c], r1[0] + r1[1] + r1[2] + r1[3]);
    atomicAdd(&s2[c], r2[0] + r2[1] + r2[2] + r2[3]);
  }
}

// ---------------- gate: v (rows 1024..1535 of qkv) *= SiLU(BN(conv(x))) ------
__global__ void gate_apply(const float* __restrict__ x,
                           const float* __restrict__ wgt,
                           const float* __restrict__ s1, const float* __restrict__ s2,
                           const float* __restrict__ gamma,
                           const float* __restrict__ beta,
                           unsigned short* __restrict__ qkv) {
  int c = blockIdx.x, b = blockIdx.y;
  __shared__ __align__(16) float plane[NPIX];
  const float* xp = x + ((size_t)b * CCH + c) * NPIX;
  unsigned short* vp = qkv + ((size_t)b * QKV_M + 2 * CCH + c) * NPIX;
  *(f32x4*)&plane[threadIdx.x * 4] = *(const f32x4*)&xp[threadIdx.x * 4];
  __syncthreads();
  float w[9];
  for (int i = 0; i < 9; i++) w[i] = wgt[c * 9 + i];
  const float invn = 1.f / 32768.f;
  float mean = s1[c] * invn;
  float var = fmaxf(s2[c] * invn - mean * mean, 0.f);
  float rstd = rsqrtf(var + 1e-5f);
  float ga = gamma[c], be = beta[c];
  for (int pi = 0; pi < 4; pi++) {
    int p = threadIdx.x + pi * 256;
    int h = p >> 5, wc = p & 31;
    float val = 0.f;
    for (int dh = -1; dh <= 1; dh++)
      for (int dw = -1; dw <= 1; dw++) {
        int hh = h + dh, ww = wc + dw;
        if (hh >= 0 && hh < 32 && ww >= 0 && ww < 32)
          val += w[(dh + 1) * 3 + dw + 1] * plane[hh * 32 + ww];
      }
    float g = (val - mean) * rstd * ga + be;
    float sg = g / (1.f + __expf(-g));      // SiLU
    vp[p] = f2bf(bf2f(vp[p]) * sg);
  }
}

// ---------------- attn_s: S=QK^T (+ fused l2norm via QQ^T/KK^T diag),
//                  softmax -> P [bh][64][64] bf16 -------------------------------
__launch_bounds__(256)
__global__ void attn_s(const unsigned short* __restrict__ qkv,
                       const float* __restrict__ temp,
                       unsigned short* __restrict__ P) {
  int bh = blockIdx.x;
  int b = bh >> 3, h = bh & 7;
  const unsigned short* Q = qkv + ((size_t)b * QKV_M + h * 64) * NPIX;
  const unsigned short* K = Q + (size_t)CCH * NPIX;
  int tid = threadIdx.x, lane = tid & 63, wave = tid >> 6;
  int quad = lane >> 4, l16 = lane & 15;

  __shared__ __align__(16) float Sf[64][65];
  __shared__ float qq[64], kk[64], invq[64], invk[64];
  __shared__ float redm[4][64], reds[4][64];

  f32x4 zero = {0.f, 0.f, 0.f, 0.f};
  f32x4 acc[4], accQ = zero, accK = zero;
  for (int j = 0; j < 4; j++) acc[j] = zero;
  for (int n0 = 0; n0 < NPIX; n0 += 32) {
    bf16x8 a  = *(const bf16x8*)&Q[(size_t)(wave * 16 + l16) * NPIX + n0 + quad * 8];
    bf16x8 ak = *(const bf16x8*)&K[(size_t)(wave * 16 + l16) * NPIX + n0 + quad * 8];
    accQ = __builtin_amdgcn_mfma_f32_16x16x32_bf16(a, a, accQ, 0, 0, 0);
    accK = __builtin_amdgcn_mfma_f32_16x16x32_bf16(ak, ak, accK, 0, 0, 0);
    for (int j = 0; j < 4; j++) {
      bf16x8 bb = *(const bf16x8*)&K[(size_t)(j * 16 + l16) * NPIX + n0 + quad * 8];
      acc[j] = __builtin_amdgcn_mfma_f32_16x16x32_bf16(a, bb, acc[j], 0, 0, 0);
    }
  }
  for (int j = 0; j < 4; j++)
    for (int r = 0; r < 4; r++)
      Sf[wave * 16 + quad * 4 + r][j * 16 + l16] = acc[j][r];
  // diagonal of Q.Q^T / K.K^T: D row=quad*4+r, col=l16 -> diag where equal
  for (int r = 0; r < 4; r++)
    if (l16 == quad * 4 + r) {
      qq[wave * 16 + l16] = accQ[r];
      kk[wave * 16 + l16] = accK[r];
    }
  __syncthreads();
  if (tid < 64) invq[tid] = 1.f / fmaxf(sqrtf(qq[tid]), 1e-12f);
  else if (tid < 128) invk[tid - 64] = 1.f / fmaxf(sqrtf(kk[tid - 64]), 1e-12f);
  __syncthreads();

  // softmax over e: 256 threads = 64 rows x 4 segments of 16
  int row = tid & 63, seg = tid >> 6;
  float fq = temp[h] * invq[row];
  float v[16], pm = -1e30f;
  for (int i = 0; i < 16; i++) {
    v[i] = Sf[row][seg * 16 + i] * fq * invk[seg * 16 + i];
    pm = fmaxf(pm, v[i]);
  }
  redm[seg][row] = pm;
  __syncthreads();
  float m = fmaxf(fmaxf(redm[0][row], redm[1][row]),
                  fmaxf(redm[2][row], redm[3][row]));
  float ps = 0.f;
  for (int i = 0; i < 16; i++) { v[i] = __expf(v[i] - m); ps += v[i]; }
  reds[seg][row] = ps;
  __syncthreads();
  float inv = 1.f / (reds[0][row] + reds[1][row] + reds[2][row] + reds[3][row]);
  union { uint4 q4[2]; unsigned short s[16]; } u;
  for (int i = 0; i < 16; i++) u.s[i] = f2bf(v[i] * inv);
  unsigned short* Pp = P + ((size_t)bh * 64 + row) * 64 + seg * 16;
  *(uint4*)&Pp[0] = u.q4[0];
  *(uint4*)&Pp[8] = u.q4[1];
}

// ---------------- attn_o: O^T[n][d] = sum_e V^T[n][e] P[d][e] ----------------
// grid = bh*4 (n-quarters); register-prefetched V, LDS-staged coalesced stores.
__launch_bounds__(256)
__global__ void attn_o(const unsigned short* __restrict__ qkv,
                       const unsigned short* __restrict__ P,
                       unsigned short* __restrict__ aoT) {
  int blk = blockIdx.x;
  int nc = blk & 3, bh = blk >> 2;
  int b = bh >> 3, h = bh & 7;
  const unsigned short* V = qkv + ((size_t)b * QKV_M + 2 * CCH + h * 64) * NPIX;
  unsigned short* Ob = aoT + (size_t)b * NPIX * CCH + h * 64;
  int tid = threadIdx.x, lane = tid & 63, wave = tid >> 6;
  int quad = lane >> 4, l16 = lane & 15;

  __shared__ __align__(16) unsigned short Vt[4][16][72];
  __shared__ __align__(16) unsigned short Ot[4][16][72];

  // P fragments (B-operand: row d = j*16+l16, k = e)
  const unsigned short* Pb = P + (size_t)bh * 64 * 64;
  bf16x8 Pf[4][2];
  for (int j = 0; j < 4; j++)
    for (int ks = 0; ks < 2; ks++)
      Pf[j][ks] = *(const bf16x8*)&Pb[(j * 16 + l16) * 64 + ks * 32 + quad * 8];

  f32x4 zero = {0.f, 0.f, 0.f, 0.f};
  int e1 = lane >> 1, noff = (lane & 1) * 8;
  int nbase = nc * 256 + wave * 64;
  int orow = lane >> 3, ocol = (lane & 7) * 8;

  union { uint4 q; unsigned short s[8]; } g0, g1, c0, c1;
  g0.q = *(const uint4*)&V[(size_t)e1 * NPIX + nbase + noff];
  g1.q = *(const uint4*)&V[(size_t)(e1 + 32) * NPIX + nbase + noff];
#pragma unroll
  for (int nt = 0; nt < 4; nt++) {
    int n0 = nbase + nt * 16;
    c0 = g0; c1 = g1;
    if (nt < 3) {
      g0.q = *(const uint4*)&V[(size_t)e1 * NPIX + n0 + 16 + noff];
      g1.q = *(const uint4*)&V[(size_t)(e1 + 32) * NPIX + n0 + 16 + noff];
    }
    for (int jj = 0; jj < 8; jj++) {
      Vt[wave][noff + jj][e1]      = c0.s[jj];
      Vt[wave][noff + jj][e1 + 32] = c1.s[jj];
    }
    bf16x8 Af0 = *(const bf16x8*)&Vt[wave][l16][quad * 8];
    bf16x8 Af1 = *(const bf16x8*)&Vt[wave][l16][32 + quad * 8];
    f32x4 oacc[4];
    for (int j = 0; j < 4; j++) {
      oacc[j] = __builtin_amdgcn_mfma_f32_16x16x32_bf16(Af0, Pf[j][0], zero, 0, 0, 0);
      oacc[j] = __builtin_amdgcn_mfma_f32_16x16x32_bf16(Af1, Pf[j][1], oacc[j], 0, 0, 0);
    }
    for (int j = 0; j < 4; j++)
      for (int r = 0; r < 4; r++)
        Ot[wave][quad * 4 + r][j * 16 + l16] = f2bf(oacc[j][r]);
    uint4 o0 = *(const uint4*)&Ot[wave][orow][ocol];
    uint4 o1 = *(const uint4*)&Ot[wave][orow + 8][ocol];
    *(uint4*)&Ob[(size_t)(n0 + orow) * CCH + ocol] = o0;
    *(uint4*)&Ob[(size_t)(n0 + orow + 8) * CCH + ocol] = o1;
  }
}

// ---------------------------------------------------------------------------
extern "C" void kernel_launch(void* const* d_in, const int* in_sizes, int n_in,
                              void* d_out, int out_size, void* d_ws, size_t ws_size,
                              hipStream_t stream) {
  const float* x     = (const float*)d_in[0];
  const float* Wq    = (const float*)d_in[1];
  const float* Wk    = (const float*)d_in[2];
  const float* Wv    = (const float*)d_in[3];
  const float* dww   = (const float*)d_in[4];
  const float* gamma = (const float*)d_in[5];
  const float* beta  = (const float*)d_in[6];
  const float* temp  = (const float*)d_in[7];
  const float* Wp    = (const float*)d_in[8];
  const float* bp    = (const float*)d_in[9];
  float* out = (float*)d_out;

  char* ws = (char*)d_ws;
  unsigned short* wcat = (unsigned short*)ws;             // [1536,512] bf16
  unsigned short* wpb  = wcat + (size_t)QKV_M * CCH;      // [512,512] bf16
  float* s1 = (float*)(wpb + (size_t)CCH * CCH);
  float* s2 = s1 + CCH;
  unsigned short* Pbuf = (unsigned short*)(s2 + CCH);     // [B*H,64,64] bf16, 2MB
  char* dyn = (char*)(Pbuf + (size_t)BATCH * HEADS * 64 * 64);
  size_t fixed = (size_t)(dyn - ws);
  size_t per_b = ((size_t)NPIX * CCH + (size_t)QKV_M * NPIX) * 2;  // 4 MB/batch
  int BC = BATCH;
  while (BC > 1 && fixed + (size_t)BC * per_b > ws_size) BC >>= 1;
  unsigned short* xT  = (unsigned short*)dyn;                  // [BC,N,C]; reused as aoT
  unsigned short* qkv = xT + (size_t)BC * NPIX * CCH;          // [BC,1536,N]

  convert_w<<<CCH * CCH / 1024, 256, 0, stream>>>(Wq, Wk, Wv, Wp, wcat, wpb);
  hipMemsetAsync(s1, 0, 2 * CCH * sizeof(float), stream);
  dw_stats<<<dim3(CCH, BATCH), 256, 0, stream>>>(x, dww, s1, s2);

  for (int b0 = 0; b0 < BATCH; b0 += BC) {
    const float* xc = x + (size_t)b0 * CCH * NPIX;
    float* outc = out + (size_t)b0 * CCH * NPIX;
    transpose_f2b<<<dim3(NPIX / 32, CCH / 32, BC), dim3(32, 8), 0, stream>>>(
        xc, xT, CCH, NPIX);
    gemm_bt<false><<<dim3(NPIX / 256, QKV_M / 256, BC), 512, 0, stream>>>(
        wcat, xT, qkv, nullptr, QKV_M, NPIX, CCH);
    attn_s<<<BC * HEADS, 256, 0, stream>>>(qkv, temp, Pbuf);
    gate_apply<<<dim3(CCH, BC), 256, 0, stream>>>(xc, dww, s1, s2, gamma, beta, qkv);
    attn_o<<<BC * HEADS * 4, 256, 0, stream>>>(qkv, Pbuf, xT);  // aoT overwrites xT
    gemm_bt<true><<<dim3(NPIX / 256, CCH / 256, BC), 512, 0, stream>>>(
        wpb, xT, outc, bp, CCH, NPIX, CCH);
  }
}

// Round 6
// 323.270 us; speedup vs baseline: 1.0628x; 1.0001x over previous
//
#include <hip/hip_runtime.h>
#include <stdint.h>

#define BATCH 32
#define CCH   512
#define NPIX  1024
#define HEADS 8
#define QKV_M 1536   // q rows 0-511, k rows 512-1023, v rows 1024-1535

typedef short bf16x8 __attribute__((ext_vector_type(8)));
typedef float f32x4 __attribute__((ext_vector_type(4)));
typedef unsigned short u16x8 __attribute__((ext_vector_type(8)));

__device__ inline float bf2f(unsigned short u) {
  union { float f; uint32_t i; } t; t.i = ((uint32_t)u) << 16; return t.f;
}
__device__ inline unsigned short f2bf(float f) {
  union { float f; uint32_t u; } t; t.f = f;
  uint32_t u = t.u;
  return (unsigned short)((u + 0x7FFFu + ((u >> 16) & 1u)) >> 16);
}

// async global->LDS, 16B per lane; LDS dest = wave-uniform base + lane*16
__device__ inline void gl_lds16(const unsigned short* g, unsigned short* l) {
  __builtin_amdgcn_global_load_lds(
      (const __attribute__((address_space(1))) uint32_t*)g,
      (__attribute__((address_space(3))) uint32_t*)l, 16, 0, 0);
}

// ---------------- weights fp32 -> bf16 (Wq|Wk|Wv concat, Wp separate) --------
__global__ void convert_w(const float* __restrict__ Wq, const float* __restrict__ Wk,
                          const float* __restrict__ Wv, const float* __restrict__ Wp,
                          unsigned short* __restrict__ wcat,
                          unsigned short* __restrict__ wpb) {
  int i = (blockIdx.x * 256 + threadIdx.x) * 4;   // over CCH*CCH = 262144
  union { ushort4 u4; unsigned short s[4]; } o;
  f32x4 a;
  a = *(const f32x4*)&Wq[i];
  for (int j = 0; j < 4; j++) o.s[j] = f2bf(a[j]);
  *(ushort4*)&wcat[i] = o.u4;
  a = *(const f32x4*)&Wk[i];
  for (int j = 0; j < 4; j++) o.s[j] = f2bf(a[j]);
  *(ushort4*)&wcat[CCH * CCH + i] = o.u4;
  a = *(const f32x4*)&Wv[i];
  for (int j = 0; j < 4; j++) o.s[j] = f2bf(a[j]);
  *(ushort4*)&wcat[2 * CCH * CCH + i] = o.u4;
  a = *(const f32x4*)&Wp[i];
  for (int j = 0; j < 4; j++) o.s[j] = f2bf(a[j]);
  *(ushort4*)&wpb[i] = o.u4;
}

// ---------------- transpose fp32 [b,C,N] -> bf16 [b,N,C] ---------------------
// Round-5 rewrite (G13): old version used 4B/lane reads + 2B/lane bf16 writes
// (Common-mistake #2, ~2x loss on 96 MB). New: 64x64 tile per block,
// 16B/lane float4 reads (64B dense per 4-lane row group), LDS [64][65] f32
// (pad breaks stride-64 bank alias), 16B/lane ushort8 stores (128B contiguous
// per pixel row; rows at 1KB stride).
__global__ void transpose_f2b(const float* __restrict__ in,
                              unsigned short* __restrict__ out) {
  __shared__ float tile[64][65];
  const int b  = blockIdx.z;
  const int p0 = blockIdx.x * 64;   // pixel base
  const int c0 = blockIdx.y * 64;   // channel base
  const float* inb = in + (size_t)b * CCH * NPIX;
  unsigned short* outb = out + (size_t)b * NPIX * CCH;
  const int t = threadIdx.x;
  const int cr = t >> 2, tl = t & 3;      // 64 channel-rows x 4 lanes
#pragma unroll
  for (int j = 0; j < 4; ++j) {
    const int off = j * 16 + tl * 4;      // 4 lanes cover 64B contiguous
    f32x4 v = *(const f32x4*)&inb[(size_t)(c0 + cr) * NPIX + p0 + off];
    tile[cr][off + 0] = v[0];
    tile[cr][off + 1] = v[1];
    tile[cr][off + 2] = v[2];
    tile[cr][off + 3] = v[3];
  }
  __syncthreads();
  const int pr = t >> 3, cc = (t & 7) * 8;  // 32 pixel-rows x 8 lanes, 2 passes
#pragma unroll
  for (int pass = 0; pass < 2; ++pass) {
    const int p = pr + pass * 32;
    union { u16x8 v; unsigned short s[8]; } o;
#pragma unroll
    for (int j = 0; j < 8; ++j) o.s[j] = f2bf(tile[cc + j][p]);
    *(u16x8*)&outb[(size_t)(p0 + p) * CCH + c0 + cc] = o.v;
  }
}

// ---------------- gemm_bt: C[b][m][n] = sum_k A[m][k]*X[b][n][k] -------------
// 256x256 tile, BK=64, 512 threads = 8 waves (2 M x 4 N), mfma 16x16x32.
// Double-buffered LDS (128 KiB), gl_lds16 staging with XOR chunk swizzle
// (conflict-free ds_read_b128, measured SQ_LDS_BANK_CONFLICT==0).
// COMPILER-SCHEDULED body; counted vmcnt(8) keeps next tile's loads in
// flight across the barrier. NOTE (rounds 1-5): three schedule structures
// (pinned 2-phase, pinned 4-phase quadrant, unpinned) all land at 72-88us
// with MfmaUtil 23-28% at this K=512 shape (8 K-tiles, 25% pro/epilogue) --
// schedule class exhausted; kernel frozen at its best (72.3us).
template <bool OUT_F32>
__launch_bounds__(512, 2)
__global__ void gemm_bt(const unsigned short* __restrict__ A,
                        const unsigned short* __restrict__ X,
                        void* __restrict__ Cout,
                        const float* __restrict__ bias,
                        int M, int N, int K) {
  __shared__ __align__(16) unsigned short As[2][256 * 64];
  __shared__ __align__(16) unsigned short Bs[2][256 * 64];
  const int b  = blockIdx.z;
  const int m0 = blockIdx.y * 256;
  const int n0 = blockIdx.x * 256;
  const unsigned short* Xb = X + (size_t)b * N * K;
  const int tid  = threadIdx.x;
  const int lane = tid & 63;
  const int wave = tid >> 6;        // 0..7
  const int wm = wave >> 2;         // 0..1  (M half: 128 rows each)
  const int wn = wave & 3;          // 0..3  (N quarter: 64 cols each)
  const int quad = lane >> 4, l16 = lane & 15;

  f32x4 acc[8][4];
  const f32x4 zero = {0.f, 0.f, 0.f, 0.f};
#pragma unroll
  for (int i = 0; i < 8; i++)
#pragma unroll
    for (int j = 0; j < 4; j++) acc[i][j] = zero;

  // staging geometry: wave w covers rows [w*32, w*32+32), 4 loads of 8 rows
  // per matrix. lane -> row += lane>>3; fetched k-chunk = (lane&7)^(lane>>3)
  // (XOR swizzle; still one 128B segment per 8-lane row-group -> coalesced).
  const int r8  = lane >> 3;
  const int swk = ((lane & 7) ^ r8) * 8;
  const unsigned short* Ag = A  + (size_t)(m0 + wave * 32 + r8) * K + swk;
  const unsigned short* Xg = Xb + (size_t)(n0 + wave * 32 + r8) * K + swk;

  const int NT = K >> 6;            // K-tiles of 64

  auto stage = [&](int kt, int bsel) {
    unsigned short* Al = &As[bsel][wave * 32 * 64];
    unsigned short* Bl = &Bs[bsel][wave * 32 * 64];
    const unsigned short* Agk = Ag + kt * 64;
    const unsigned short* Xgk = Xg + kt * 64;
#pragma unroll
    for (int i = 0; i < 4; ++i) {
      gl_lds16(Agk + (size_t)i * 8 * K, Al + i * 8 * 64);
      gl_lds16(Xgk + (size_t)i * 8 * K, Bl + i * 8 * 64);
    }
  };

  // prologue: tiles 0 and 1 in flight; wait tile 0 (tile 1's 8 stay in flight)
  stage(0, 0);
  if (NT > 1) stage(1, 1);
  asm volatile("s_waitcnt vmcnt(8)" ::: "memory");
  __builtin_amdgcn_s_barrier();

  for (int t = 0; t < NT; ++t) {
    const int cur = t & 1;
    const unsigned short* Asl = As[cur];
    const unsigned short* Bsl = Bs[cur];

    // -------- unpinned compute region: 24 ds_read_b128 + 64 MFMA --------
    {
      bf16x8 a0[8], b0[4];
      const int ch0 = ((0 * 4 + quad) ^ (l16 & 7)) * 8;
#pragma unroll
      for (int ii = 0; ii < 8; ++ii)
        a0[ii] = *(const bf16x8*)&Asl[(wm * 128 + ii * 16 + l16) * 64 + ch0];
#pragma unroll
      for (int jj = 0; jj < 4; ++jj)
        b0[jj] = *(const bf16x8*)&Bsl[(wn * 64 + jj * 16 + l16) * 64 + ch0];

      bf16x8 a1[8], b1[4];
      const int ch1 = ((1 * 4 + quad) ^ (l16 & 7)) * 8;
#pragma unroll
      for (int ii = 0; ii < 8; ++ii)
        a1[ii] = *(const bf16x8*)&Asl[(wm * 128 + ii * 16 + l16) * 64 + ch1];
#pragma unroll
      for (int jj = 0; jj < 4; ++jj)
        b1[jj] = *(const bf16x8*)&Bsl[(wn * 64 + jj * 16 + l16) * 64 + ch1];

#pragma unroll
      for (int ii = 0; ii < 8; ++ii)
#pragma unroll
        for (int jj = 0; jj < 4; ++jj)
          acc[ii][jj] = __builtin_amdgcn_mfma_f32_16x16x32_bf16(
              a0[ii], b0[jj], acc[ii][jj], 0, 0, 0);
#pragma unroll
      for (int ii = 0; ii < 8; ++ii)
#pragma unroll
        for (int jj = 0; jj < 4; ++jj)
          acc[ii][jj] = __builtin_amdgcn_mfma_f32_16x16x32_bf16(
              a1[ii], b1[jj], acc[ii][jj], 0, 0, 0);
    }

    // -------- sync skeleton: 2 barriers + counted vmcnt per K-tile --------
    __builtin_amdgcn_s_barrier();      // all waves consumed buf cur
    if (t + 2 < NT) {
      stage(t + 2, cur);               // overwrite drained buffer
      asm volatile("s_waitcnt vmcnt(8)" ::: "memory");  // tile t+1 landed
    } else if (t + 1 < NT) {
      asm volatile("s_waitcnt vmcnt(0)" ::: "memory");  // final drain
    }
    __builtin_amdgcn_s_barrier();      // publish tile t+1
  }

  // C/D layout: row = quad*4+reg, col = l16
#pragma unroll
  for (int i = 0; i < 8; ++i) {
#pragma unroll
    for (int r = 0; r < 4; ++r) {
      const int gm = m0 + wm * 128 + i * 16 + quad * 4 + r;
      if constexpr (OUT_F32) {
        const float bv = bias[gm];
        float* Co = (float*)Cout + (size_t)b * M * N + (size_t)gm * N +
                    n0 + wn * 64 + l16;
#pragma unroll
        for (int j = 0; j < 4; ++j) Co[j * 16] = acc[i][j][r] + bv;
      } else {
        unsigned short* Co = (unsigned short*)Cout + (size_t)b * M * N +
                             (size_t)gm * N + n0 + wn * 64 + l16;
#pragma unroll
        for (int j = 0; j < 4; ++j) Co[j * 16] = f2bf(acc[i][j][r]);
      }
    }
  }
}

// ---------------- depthwise 3x3 per-channel stats (sum, sumsq) ---------------
__global__ void dw_stats(const float* __restrict__ x,
                         const float* __restrict__ wgt,
                         float* __restrict__ s1, float* __restrict__ s2) {
  int c = blockIdx.x, b = blockIdx.y;
  __shared__ __align__(16) float plane[NPIX];
  const float* xp = x + ((size_t)b * CCH + c) * NPIX;
  *(f32x4*)&plane[threadIdx.x * 4] = *(const f32x4*)&xp[threadIdx.x * 4];
  __syncthreads();
  float w[9];
  for (int i = 0; i < 9; i++) w[i] = wgt[c * 9 + i];
  float a1 = 0.f, a2 = 0.f;
  for (int pi = 0; pi < 4; pi++) {
    int p = threadIdx.x + pi * 256;
    int h = p >> 5, wc = p & 31;
    float v = 0.f;
    for (int dh = -1; dh <= 1; dh++)
      for (int dw = -1; dw <= 1; dw++) {
        int hh = h + dh, ww = wc + dw;
        if (hh >= 0 && hh < 32 && ww >= 0 && ww < 32)
          v += w[(dh + 1) * 3 + dw + 1] * plane[hh * 32 + ww];
      }
    a1 += v; a2 += v * v;
  }
  for (int off = 32; off > 0; off >>= 1) {
    a1 += __shfl_down(a1, off);
    a2 += __shfl_down(a2, off);
  }
  __shared__ float r1[4], r2[4];
  int wv = threadIdx.x >> 6;
  if ((threadIdx.x & 63) == 0) { r1[wv] = a1; r2[wv] = a2; }
  __syncthreads();
  if (threadIdx.x == 0) {
    atomicAdd(&s1[c], r1[0] + r1[1] + r1[2] + r1[3]);
    atomicAdd(&s2[c], r2[0] + r2[1] + r2[2] + r2[3]);
  }
}

// ---------------- gate: v (rows 1024..1535 of qkv) *= SiLU(BN(conv(x))) ------
// Round-5 rewrite (G13): old version did 2B/lane scalar bf16 rmw on 64 MB of
// qkv-V traffic. New: each thread owns 4 CONSECUTIVE pixels -> one ushort4
// load + one ushort4 store (8B/lane coalesced). Conv math/guards unchanged.
__global__ void gate_apply(const float* __restrict__ x,
                           const float* __restrict__ wgt,
                           const float* __restrict__ s1, const float* __restrict__ s2,
                           const float* __restrict__ gamma,
                           const float* __restrict__ beta,
                           unsigned short* __restrict__ qkv) {
  int c = blockIdx.x, b = blockIdx.y;
  __shared__ __align__(16) float plane[NPIX];
  const float* xp = x + ((size_t)b * CCH + c) * NPIX;
  *(f32x4*)&plane[threadIdx.x * 4] = *(const f32x4*)&xp[threadIdx.x * 4];
  __syncthreads();
  float w[9];
  for (int i = 0; i < 9; i++) w[i] = wgt[c * 9 + i];
  const float invn = 1.f / 32768.f;
  float mean = s1[c] * invn;
  float var = fmaxf(s2[c] * invn - mean * mean, 0.f);
  float rstd = rsqrtf(var + 1e-5f);
  float ga = gamma[c], be = beta[c];

  const int t = threadIdx.x;
  const int h = t >> 3, w0 = (t & 7) * 4;       // 4 consecutive pixels per thread
  unsigned short* vp = qkv + ((size_t)b * QKV_M + 2 * CCH + c) * NPIX + h * 32 + w0;
  union { ushort4 q; unsigned short s[4]; } vv;
  vv.q = *(const ushort4*)vp;
#pragma unroll
  for (int i = 0; i < 4; ++i) {
    const int wc = w0 + i;
    float val = 0.f;
    for (int dh = -1; dh <= 1; dh++)
      for (int dw = -1; dw <= 1; dw++) {
        int hh = h + dh, ww = wc + dw;
        if (hh >= 0 && hh < 32 && ww >= 0 && ww < 32)
          val += w[(dh + 1) * 3 + dw + 1] * plane[hh * 32 + ww];
      }
    float g = (val - mean) * rstd * ga + be;
    float sg = g / (1.f + __expf(-g));      // SiLU
    vv.s[i] = f2bf(bf2f(vv.s[i]) * sg);
  }
  *(ushort4*)vp = vv.q;
}

// ---------------- attn_s: S=QK^T (+ fused l2norm via QQ^T/KK^T diag),
//                  softmax -> P [bh][64][64] bf16 -------------------------------
__launch_bounds__(256)
__global__ void attn_s(const unsigned short* __restrict__ qkv,
                       const float* __restrict__ temp,
                       unsigned short* __restrict__ P) {
  int bh = blockIdx.x;
  int b = bh >> 3, h = bh & 7;
  const unsigned short* Q = qkv + ((size_t)b * QKV_M + h * 64) * NPIX;
  const unsigned short* K = Q + (size_t)CCH * NPIX;
  int tid = threadIdx.x, lane = tid & 63, wave = tid >> 6;
  int quad = lane >> 4, l16 = lane & 15;

  __shared__ __align__(16) float Sf[64][65];
  __shared__ float qq[64], kk[64], invq[64], invk[64];
  __shared__ float redm[4][64], reds[4][64];

  f32x4 zero = {0.f, 0.f, 0.f, 0.f};
  f32x4 acc[4], accQ = zero, accK = zero;
  for (int j = 0; j < 4; j++) acc[j] = zero;
  for (int n0 = 0; n0 < NPIX; n0 += 32) {
    bf16x8 a  = *(const bf16x8*)&Q[(size_t)(wave * 16 + l16) * NPIX + n0 + quad * 8];
    bf16x8 ak = *(const bf16x8*)&K[(size_t)(wave * 16 + l16) * NPIX + n0 + quad * 8];
    accQ = __builtin_amdgcn_mfma_f32_16x16x32_bf16(a, a, accQ, 0, 0, 0);
    accK = __builtin_amdgcn_mfma_f32_16x16x32_bf16(ak, ak, accK, 0, 0, 0);
    for (int j = 0; j < 4; j++) {
      bf16x8 bb = *(const bf16x8*)&K[(size_t)(j * 16 + l16) * NPIX + n0 + quad * 8];
      acc[j] = __builtin_amdgcn_mfma_f32_16x16x32_bf16(a, bb, acc[j], 0, 0, 0);
    }
  }
  for (int j = 0; j < 4; j++)
    for (int r = 0; r < 4; r++)
      Sf[wave * 16 + quad * 4 + r][j * 16 + l16] = acc[j][r];
  // diagonal of Q.Q^T / K.K^T: D row=quad*4+r, col=l16 -> diag where equal
  for (int r = 0; r < 4; r++)
    if (l16 == quad * 4 + r) {
      qq[wave * 16 + l16] = accQ[r];
      kk[wave * 16 + l16] = accK[r];
    }
  __syncthreads();
  if (tid < 64) invq[tid] = 1.f / fmaxf(sqrtf(qq[tid]), 1e-12f);
  else if (tid < 128) invk[tid - 64] = 1.f / fmaxf(sqrtf(kk[tid - 64]), 1e-12f);
  __syncthreads();

  // softmax over e: 256 threads = 64 rows x 4 segments of 16
  int row = tid & 63, seg = tid >> 6;
  float fq = temp[h] * invq[row];
  float v[16], pm = -1e30f;
  for (int i = 0; i < 16; i++) {
    v[i] = Sf[row][seg * 16 + i] * fq * invk[seg * 16 + i];
    pm = fmaxf(pm, v[i]);
  }
  redm[seg][row] = pm;
  __syncthreads();
  float m = fmaxf(fmaxf(redm[0][row], redm[1][row]),
                  fmaxf(redm[2][row], redm[3][row]));
  float ps = 0.f;
  for (int i = 0; i < 16; i++) { v[i] = __expf(v[i] - m); ps += v[i]; }
  reds[seg][row] = ps;
  __syncthreads();
  float inv = 1.f / (reds[0][row] + reds[1][row] + reds[2][row] + reds[3][row]);
  union { uint4 q4[2]; unsigned short s[16]; } u;
  for (int i = 0; i < 16; i++) u.s[i] = f2bf(v[i] * inv);
  unsigned short* Pp = P + ((size_t)bh * 64 + row) * 64 + seg * 16;
  *(uint4*)&Pp[0] = u.q4[0];
  *(uint4*)&Pp[8] = u.q4[1];
}

// ---------------- attn_o: O^T[n][d] = sum_e V^T[n][e] P[d][e] ----------------
// grid = bh*4 (n-quarters); register-prefetched V, LDS-staged coalesced stores.
__launch_bounds__(256)
__global__ void attn_o(const unsigned short* __restrict__ qkv,
                       const unsigned short* __restrict__ P,
                       unsigned short* __restrict__ aoT) {
  int blk = blockIdx.x;
  int nc = blk & 3, bh = blk >> 2;
  int b = bh >> 3, h = bh & 7;
  const unsigned short* V = qkv + ((size_t)b * QKV_M + 2 * CCH + h * 64) * NPIX;
  unsigned short* Ob = aoT + (size_t)b * NPIX * CCH + h * 64;
  int tid = threadIdx.x, lane = tid & 63, wave = tid >> 6;
  int quad = lane >> 4, l16 = lane & 15;

  __shared__ __align__(16) unsigned short Vt[4][16][72];
  __shared__ __align__(16) unsigned short Ot[4][16][72];

  // P fragments (B-operand: row d = j*16+l16, k = e)
  const unsigned short* Pb = P + (size_t)bh * 64 * 64;
  bf16x8 Pf[4][2];
  for (int j = 0; j < 4; j++)
    for (int ks = 0; ks < 2; ks++)
      Pf[j][ks] = *(const bf16x8*)&Pb[(j * 16 + l16) * 64 + ks * 32 + quad * 8];

  f32x4 zero = {0.f, 0.f, 0.f, 0.f};
  int e1 = lane >> 1, noff = (lane & 1) * 8;
  int nbase = nc * 256 + wave * 64;
  int orow = lane >> 3, ocol = (lane & 7) * 8;

  union { uint4 q; unsigned short s[8]; } g0, g1, c0, c1;
  g0.q = *(const uint4*)&V[(size_t)e1 * NPIX + nbase + noff];
  g1.q = *(const uint4*)&V[(size_t)(e1 + 32) * NPIX + nbase + noff];
#pragma unroll
  for (int nt = 0; nt < 4; nt++) {
    int n0 = nbase + nt * 16;
    c0 = g0; c1 = g1;
    if (nt < 3) {
      g0.q = *(const uint4*)&V[(size_t)e1 * NPIX + n0 + 16 + noff];
      g1.q = *(const uint4*)&V[(size_t)(e1 + 32) * NPIX + n0 + 16 + noff];
    }
    for (int jj = 0; jj < 8; jj++) {
      Vt[wave][noff + jj][e1]      = c0.s[jj];
      Vt[wave][noff + jj][e1 + 32] = c1.s[jj];
    }
    bf16x8 Af0 = *(const bf16x8*)&Vt[wave][l16][quad * 8];
    bf16x8 Af1 = *(const bf16x8*)&Vt[wave][l16][32 + quad * 8];
    f32x4 oacc[4];
    for (int j = 0; j < 4; j++) {
      oacc[j] = __builtin_amdgcn_mfma_f32_16x16x32_bf16(Af0, Pf[j][0], zero, 0, 0, 0);
      oacc[j] = __builtin_amdgcn_mfma_f32_16x16x32_bf16(Af1, Pf[j][1], oacc[j], 0, 0, 0);
    }
    for (int j = 0; j < 4; j++)
      for (int r = 0; r < 4; r++)
        Ot[wave][quad * 4 + r][j * 16 + l16] = f2bf(oacc[j][r]);
    uint4 o0 = *(const uint4*)&Ot[wave][orow][ocol];
    uint4 o1 = *(const uint4*)&Ot[wave][orow + 8][ocol];
    *(uint4*)&Ob[(size_t)(n0 + orow) * CCH + ocol] = o0;
    *(uint4*)&Ob[(size_t)(n0 + orow + 8) * CCH + ocol] = o1;
  }
}

// ---------------------------------------------------------------------------
extern "C" void kernel_launch(void* const* d_in, const int* in_sizes, int n_in,
                              void* d_out, int out_size, void* d_ws, size_t ws_size,
                              hipStream_t stream) {
  const float* x     = (const float*)d_in[0];
  const float* Wq    = (const float*)d_in[1];
  const float* Wk    = (const float*)d_in[2];
  const float* Wv    = (const float*)d_in[3];
  const float* dww   = (const float*)d_in[4];
  const float* gamma = (const float*)d_in[5];
  const float* beta  = (const float*)d_in[6];
  const float* temp  = (const float*)d_in[7];
  const float* Wp    = (const float*)d_in[8];
  const float* bp    = (const float*)d_in[9];
  float* out = (float*)d_out;

  char* ws = (char*)d_ws;
  unsigned short* wcat = (unsigned short*)ws;             // [1536,512] bf16
  unsigned short* wpb  = wcat + (size_t)QKV_M * CCH;      // [512,512] bf16
  float* s1 = (float*)(wpb + (size_t)CCH * CCH);
  float* s2 = s1 + CCH;
  unsigned short* Pbuf = (unsigned short*)(s2 + CCH);     // [B*H,64,64] bf16, 2MB
  char* dyn = (char*)(Pbuf + (size_t)BATCH * HEADS * 64 * 64);
  size_t fixed = (size_t)(dyn - ws);
  size_t per_b = ((size_t)NPIX * CCH + (size_t)QKV_M * NPIX) * 2;  // 4 MB/batch
  int BC = BATCH;
  while (BC > 1 && fixed + (size_t)BC * per_b > ws_size) BC >>= 1;
  unsigned short* xT  = (unsigned short*)dyn;                  // [BC,N,C]; reused as aoT
  unsigned short* qkv = xT + (size_t)BC * NPIX * CCH;          // [BC,1536,N]

  convert_w<<<CCH * CCH / 1024, 256, 0, stream>>>(Wq, Wk, Wv, Wp, wcat, wpb);
  hipMemsetAsync(s1, 0, 2 * CCH * sizeof(float), stream);
  dw_stats<<<dim3(CCH, BATCH), 256, 0, stream>>>(x, dww, s1, s2);

  for (int b0 = 0; b0 < BATCH; b0 += BC) {
    const float* xc = x + (size_t)b0 * CCH * NPIX;
    float* outc = out + (size_t)b0 * CCH * NPIX;
    transpose_f2b<<<dim3(NPIX / 64, CCH / 64, BC), 256, 0, stream>>>(xc, xT);
    gemm_bt<false><<<dim3(NPIX / 256, QKV_M / 256, BC), 512, 0, stream>>>(
        wcat, xT, qkv, nullptr, QKV_M, NPIX, CCH);
    attn_s<<<BC * HEADS, 256, 0, stream>>>(qkv, temp, Pbuf);
    gate_apply<<<dim3(CCH, BC), 256, 0, stream>>>(xc, dww, s1, s2, gamma, beta, qkv);
    attn_o<<<BC * HEADS * 4, 256, 0, stream>>>(qkv, Pbuf, xT);  // aoT overwrites xT
    gemm_bt<true><<<dim3(NPIX / 256, CCH / 256, BC), 512, 0, stream>>>(
        wpb, xT, outc, bp, CCH, NPIX, CCH);
  }
}

// Round 7
// 322.851 us; speedup vs baseline: 1.0642x; 1.0013x over previous
//
#include <hip/hip_runtime.h>
#include <stdint.h>

#define BATCH 32
#define CCH   512
#define NPIX  1024
#define HEADS 8
#define QKV_M 1536   // q rows 0-511, k rows 512-1023, v rows 1024-1535

typedef short bf16x8 __attribute__((ext_vector_type(8)));
typedef float f32x4 __attribute__((ext_vector_type(4)));
typedef unsigned short u16x8 __attribute__((ext_vector_type(8)));

__device__ inline float bf2f(unsigned short u) {
  union { float f; uint32_t i; } t; t.i = ((uint32_t)u) << 16; return t.f;
}
__device__ inline unsigned short f2bf(float f) {
  union { float f; uint32_t u; } t; t.f = f;
  uint32_t u = t.u;
  return (unsigned short)((u + 0x7FFFu + ((u >> 16) & 1u)) >> 16);
}

// async global->LDS, 16B per lane; LDS dest = wave-uniform base + lane*16
__device__ inline void gl_lds16(const unsigned short* g, unsigned short* l) {
  __builtin_amdgcn_global_load_lds(
      (const __attribute__((address_space(1))) uint32_t*)g,
      (__attribute__((address_space(3))) uint32_t*)l, 16, 0, 0);
}

// ---------------- weights fp32 -> bf16 (Wq|Wk|Wv concat, Wp separate) --------
__global__ void convert_w(const float* __restrict__ Wq, const float* __restrict__ Wk,
                          const float* __restrict__ Wv, const float* __restrict__ Wp,
                          unsigned short* __restrict__ wcat,
                          unsigned short* __restrict__ wpb) {
  int i = (blockIdx.x * 256 + threadIdx.x) * 4;   // over CCH*CCH = 262144
  union { ushort4 u4; unsigned short s[4]; } o;
  f32x4 a;
  a = *(const f32x4*)&Wq[i];
  for (int j = 0; j < 4; j++) o.s[j] = f2bf(a[j]);
  *(ushort4*)&wcat[i] = o.u4;
  a = *(const f32x4*)&Wk[i];
  for (int j = 0; j < 4; j++) o.s[j] = f2bf(a[j]);
  *(ushort4*)&wcat[CCH * CCH + i] = o.u4;
  a = *(const f32x4*)&Wv[i];
  for (int j = 0; j < 4; j++) o.s[j] = f2bf(a[j]);
  *(ushort4*)&wcat[2 * CCH * CCH + i] = o.u4;
  a = *(const f32x4*)&Wp[i];
  for (int j = 0; j < 4; j++) o.s[j] = f2bf(a[j]);
  *(ushort4*)&wpb[i] = o.u4;
}

// ---------------- transpose fp32 [b,C,N] -> bf16 [b,N,C] ---------------------
__global__ void transpose_f2b(const float* __restrict__ in,
                              unsigned short* __restrict__ out) {
  __shared__ float tile[64][65];
  const int b  = blockIdx.z;
  const int p0 = blockIdx.x * 64;   // pixel base
  const int c0 = blockIdx.y * 64;   // channel base
  const float* inb = in + (size_t)b * CCH * NPIX;
  unsigned short* outb = out + (size_t)b * NPIX * CCH;
  const int t = threadIdx.x;
  const int cr = t >> 2, tl = t & 3;      // 64 channel-rows x 4 lanes
#pragma unroll
  for (int j = 0; j < 4; ++j) {
    const int off = j * 16 + tl * 4;      // 4 lanes cover 64B contiguous
    f32x4 v = *(const f32x4*)&inb[(size_t)(c0 + cr) * NPIX + p0 + off];
    tile[cr][off + 0] = v[0];
    tile[cr][off + 1] = v[1];
    tile[cr][off + 2] = v[2];
    tile[cr][off + 3] = v[3];
  }
  __syncthreads();
  const int pr = t >> 3, cc = (t & 7) * 8;  // 32 pixel-rows x 8 lanes, 2 passes
#pragma unroll
  for (int pass = 0; pass < 2; ++pass) {
    const int p = pr + pass * 32;
    union { u16x8 v; unsigned short s[8]; } o;
#pragma unroll
    for (int j = 0; j < 8; ++j) o.s[j] = f2bf(tile[cc + j][p]);
    *(u16x8*)&outb[(size_t)(p0 + p) * CCH + c0 + cc] = o.v;
  }
}

// ---------------- gemm_bt: C[b][m][n] = sum_k A[m][k]*X[b][n][k] -------------
// 256x256 tile, BK=64, 512 threads = 8 waves (2 M x 4 N), mfma 16x16x32.
// Frozen at its round-5 best (72.3us): schedule class exhausted at K=512.
template <bool OUT_F32>
__launch_bounds__(512, 2)
__global__ void gemm_bt(const unsigned short* __restrict__ A,
                        const unsigned short* __restrict__ X,
                        void* __restrict__ Cout,
                        const float* __restrict__ bias,
                        int M, int N, int K) {
  __shared__ __align__(16) unsigned short As[2][256 * 64];
  __shared__ __align__(16) unsigned short Bs[2][256 * 64];
  const int b  = blockIdx.z;
  const int m0 = blockIdx.y * 256;
  const int n0 = blockIdx.x * 256;
  const unsigned short* Xb = X + (size_t)b * N * K;
  const int tid  = threadIdx.x;
  const int lane = tid & 63;
  const int wave = tid >> 6;        // 0..7
  const int wm = wave >> 2;         // 0..1  (M half: 128 rows each)
  const int wn = wave & 3;          // 0..3  (N quarter: 64 cols each)
  const int quad = lane >> 4, l16 = lane & 15;

  f32x4 acc[8][4];
  const f32x4 zero = {0.f, 0.f, 0.f, 0.f};
#pragma unroll
  for (int i = 0; i < 8; i++)
#pragma unroll
    for (int j = 0; j < 4; j++) acc[i][j] = zero;

  const int r8  = lane >> 3;
  const int swk = ((lane & 7) ^ r8) * 8;
  const unsigned short* Ag = A  + (size_t)(m0 + wave * 32 + r8) * K + swk;
  const unsigned short* Xg = Xb + (size_t)(n0 + wave * 32 + r8) * K + swk;

  const int NT = K >> 6;            // K-tiles of 64

  auto stage = [&](int kt, int bsel) {
    unsigned short* Al = &As[bsel][wave * 32 * 64];
    unsigned short* Bl = &Bs[bsel][wave * 32 * 64];
    const unsigned short* Agk = Ag + kt * 64;
    const unsigned short* Xgk = Xg + kt * 64;
#pragma unroll
    for (int i = 0; i < 4; ++i) {
      gl_lds16(Agk + (size_t)i * 8 * K, Al + i * 8 * 64);
      gl_lds16(Xgk + (size_t)i * 8 * K, Bl + i * 8 * 64);
    }
  };

  stage(0, 0);
  if (NT > 1) stage(1, 1);
  asm volatile("s_waitcnt vmcnt(8)" ::: "memory");
  __builtin_amdgcn_s_barrier();

  for (int t = 0; t < NT; ++t) {
    const int cur = t & 1;
    const unsigned short* Asl = As[cur];
    const unsigned short* Bsl = Bs[cur];

    {
      bf16x8 a0[8], b0[4];
      const int ch0 = ((0 * 4 + quad) ^ (l16 & 7)) * 8;
#pragma unroll
      for (int ii = 0; ii < 8; ++ii)
        a0[ii] = *(const bf16x8*)&Asl[(wm * 128 + ii * 16 + l16) * 64 + ch0];
#pragma unroll
      for (int jj = 0; jj < 4; ++jj)
        b0[jj] = *(const bf16x8*)&Bsl[(wn * 64 + jj * 16 + l16) * 64 + ch0];

      bf16x8 a1[8], b1[4];
      const int ch1 = ((1 * 4 + quad) ^ (l16 & 7)) * 8;
#pragma unroll
      for (int ii = 0; ii < 8; ++ii)
        a1[ii] = *(const bf16x8*)&Asl[(wm * 128 + ii * 16 + l16) * 64 + ch1];
#pragma unroll
      for (int jj = 0; jj < 4; ++jj)
        b1[jj] = *(const bf16x8*)&Bsl[(wn * 64 + jj * 16 + l16) * 64 + ch1];

#pragma unroll
      for (int ii = 0; ii < 8; ++ii)
#pragma unroll
        for (int jj = 0; jj < 4; ++jj)
          acc[ii][jj] = __builtin_amdgcn_mfma_f32_16x16x32_bf16(
              a0[ii], b0[jj], acc[ii][jj], 0, 0, 0);
#pragma unroll
      for (int ii = 0; ii < 8; ++ii)
#pragma unroll
        for (int jj = 0; jj < 4; ++jj)
          acc[ii][jj] = __builtin_amdgcn_mfma_f32_16x16x32_bf16(
              a1[ii], b1[jj], acc[ii][jj], 0, 0, 0);
    }

    __builtin_amdgcn_s_barrier();      // all waves consumed buf cur
    if (t + 2 < NT) {
      stage(t + 2, cur);               // overwrite drained buffer
      asm volatile("s_waitcnt vmcnt(8)" ::: "memory");  // tile t+1 landed
    } else if (t + 1 < NT) {
      asm volatile("s_waitcnt vmcnt(0)" ::: "memory");  // final drain
    }
    __builtin_amdgcn_s_barrier();      // publish tile t+1
  }

  // C/D layout: row = quad*4+reg, col = l16
#pragma unroll
  for (int i = 0; i < 8; ++i) {
#pragma unroll
    for (int r = 0; r < 4; ++r) {
      const int gm = m0 + wm * 128 + i * 16 + quad * 4 + r;
      if constexpr (OUT_F32) {
        const float bv = bias[gm];
        float* Co = (float*)Cout + (size_t)b * M * N + (size_t)gm * N +
                    n0 + wn * 64 + l16;
#pragma unroll
        for (int j = 0; j < 4; ++j) Co[j * 16] = acc[i][j][r] + bv;
      } else {
        unsigned short* Co = (unsigned short*)Cout + (size_t)b * M * N +
                             (size_t)gm * N + n0 + wn * 64 + l16;
#pragma unroll
        for (int j = 0; j < 4; ++j) Co[j * 16] = f2bf(acc[i][j][r]);
      }
    }
  }
}

// ---------------- depthwise 3x3 per-channel stats (sum, sumsq) ---------------
__global__ void dw_stats(const float* __restrict__ x,
                         const float* __restrict__ wgt,
                         float* __restrict__ s1, float* __restrict__ s2) {
  int c = blockIdx.x, b = blockIdx.y;
  __shared__ __align__(16) float plane[NPIX];
  const float* xp = x + ((size_t)b * CCH + c) * NPIX;
  *(f32x4*)&plane[threadIdx.x * 4] = *(const f32x4*)&xp[threadIdx.x * 4];
  __syncthreads();
  float w[9];
  for (int i = 0; i < 9; i++) w[i] = wgt[c * 9 + i];
  float a1 = 0.f, a2 = 0.f;
  for (int pi = 0; pi < 4; pi++) {
    int p = threadIdx.x + pi * 256;
    int h = p >> 5, wc = p & 31;
    float v = 0.f;
    for (int dh = -1; dh <= 1; dh++)
      for (int dw = -1; dw <= 1; dw++) {
        int hh = h + dh, ww = wc + dw;
        if (hh >= 0 && hh < 32 && ww >= 0 && ww < 32)
          v += w[(dh + 1) * 3 + dw + 1] * plane[hh * 32 + ww];
      }
    a1 += v; a2 += v * v;
  }
  for (int off = 32; off > 0; off >>= 1) {
    a1 += __shfl_down(a1, off);
    a2 += __shfl_down(a2, off);
  }
  __shared__ float r1[4], r2[4];
  int wv = threadIdx.x >> 6;
  if ((threadIdx.x & 63) == 0) { r1[wv] = a1; r2[wv] = a2; }
  __syncthreads();
  if (threadIdx.x == 0) {
    atomicAdd(&s1[c], r1[0] + r1[1] + r1[2] + r1[3]);
    atomicAdd(&s2[c], r2[0] + r2[1] + r2[2] + r2[3]);
  }
}

// ---------------- gate: v (rows 1024..1535 of qkv) *= SiLU(BN(conv(x))) ------
__global__ void gate_apply(const float* __restrict__ x,
                           const float* __restrict__ wgt,
                           const float* __restrict__ s1, const float* __restrict__ s2,
                           const float* __restrict__ gamma,
                           const float* __restrict__ beta,
                           unsigned short* __restrict__ qkv) {
  int c = blockIdx.x, b = blockIdx.y;
  __shared__ __align__(16) float plane[NPIX];
  const float* xp = x + ((size_t)b * CCH + c) * NPIX;
  *(f32x4*)&plane[threadIdx.x * 4] = *(const f32x4*)&xp[threadIdx.x * 4];
  __syncthreads();
  float w[9];
  for (int i = 0; i < 9; i++) w[i] = wgt[c * 9 + i];
  const float invn = 1.f / 32768.f;
  float mean = s1[c] * invn;
  float var = fmaxf(s2[c] * invn - mean * mean, 0.f);
  float rstd = rsqrtf(var + 1e-5f);
  float ga = gamma[c], be = beta[c];

  const int t = threadIdx.x;
  const int h = t >> 3, w0 = (t & 7) * 4;       // 4 consecutive pixels per thread
  unsigned short* vp = qkv + ((size_t)b * QKV_M + 2 * CCH + c) * NPIX + h * 32 + w0;
  union { ushort4 q; unsigned short s[4]; } vv;
  vv.q = *(const ushort4*)vp;
#pragma unroll
  for (int i = 0; i < 4; ++i) {
    const int wc = w0 + i;
    float val = 0.f;
    for (int dh = -1; dh <= 1; dh++)
      for (int dw = -1; dw <= 1; dw++) {
        int hh = h + dh, ww = wc + dw;
        if (hh >= 0 && hh < 32 && ww >= 0 && ww < 32)
          val += w[(dh + 1) * 3 + dw + 1] * plane[hh * 32 + ww];
      }
    float g = (val - mean) * rstd * ga + be;
    float sg = g / (1.f + __expf(-g));      // SiLU
    vv.s[i] = f2bf(bf2f(vv.s[i]) * sg);
  }
  *(ushort4*)vp = vv.q;
}

// ---------------- attn_s: S=QK^T (+ fused l2norm via QQ^T/KK^T diag),
//                  softmax -> P [bh][64][64] bf16 -------------------------------
// Round-7 restructure (occupancy bisection): old version was 256 thr = 1
// wave/SIMD (12.5% occupancy) with a 32-iteration serial {load->MFMA} loop --
// nothing to hide HBM latency behind. New: 1024 thr = 16 waves; wave (r16,ns)
// computes rows r16*16..+16 over n-slice ns*256..+256 (8 iters), partials in
// LDS Sp[4][64][68] (stride-68 pad -> D-write is exactly 2 lanes/bank = free),
// then 1024-thread cross-slice reduce + 16-segment softmax.
__launch_bounds__(1024)
__global__ void attn_s(const unsigned short* __restrict__ qkv,
                       const float* __restrict__ temp,
                       unsigned short* __restrict__ P) {
  int bh = blockIdx.x;
  int b = bh >> 3, h = bh & 7;
  const unsigned short* Q = qkv + ((size_t)b * QKV_M + h * 64) * NPIX;
  const unsigned short* K = Q + (size_t)CCH * NPIX;
  int tid = threadIdx.x, lane = tid & 63, wave = tid >> 6;  // wave 0..15
  int r16 = wave & 3;        // row group (16 rows)
  int ns  = wave >> 2;       // n-slice (256 cols of N)
  int quad = lane >> 4, l16 = lane & 15;

  __shared__ float Sp[4][64][68];          // [ns][row][col], padded
  __shared__ float qqp[4][64], kkp[4][64];
  __shared__ float invq[64], invk[64];
  __shared__ float redm[16][64], reds[16][64];

  f32x4 zero = {0.f, 0.f, 0.f, 0.f};
  f32x4 acc[4], accQ = zero, accK = zero;
#pragma unroll
  for (int j = 0; j < 4; j++) acc[j] = zero;

  const int nbase = ns * 256;
  for (int n0 = nbase; n0 < nbase + 256; n0 += 32) {
    bf16x8 a  = *(const bf16x8*)&Q[(size_t)(r16 * 16 + l16) * NPIX + n0 + quad * 8];
    bf16x8 ak = *(const bf16x8*)&K[(size_t)(r16 * 16 + l16) * NPIX + n0 + quad * 8];
    accQ = __builtin_amdgcn_mfma_f32_16x16x32_bf16(a, a, accQ, 0, 0, 0);
    accK = __builtin_amdgcn_mfma_f32_16x16x32_bf16(ak, ak, accK, 0, 0, 0);
#pragma unroll
    for (int j = 0; j < 4; j++) {
      bf16x8 bb = *(const bf16x8*)&K[(size_t)(j * 16 + l16) * NPIX + n0 + quad * 8];
      acc[j] = __builtin_amdgcn_mfma_f32_16x16x32_bf16(a, bb, acc[j], 0, 0, 0);
    }
  }
  // partials: D row = quad*4+r (within group), col = l16
#pragma unroll
  for (int j = 0; j < 4; j++)
#pragma unroll
    for (int r = 0; r < 4; r++)
      Sp[ns][r16 * 16 + quad * 4 + r][j * 16 + l16] = acc[j][r];
#pragma unroll
  for (int r = 0; r < 4; r++)
    if (l16 == quad * 4 + r) {
      qqp[ns][r16 * 16 + l16] = accQ[r];
      kkp[ns][r16 * 16 + l16] = accK[r];
    }
  __syncthreads();

  // cross-slice reduce: 1024 threads cover 64x64; thread = (row, 4-col chunk)
  const int row = tid >> 4, c0 = (tid & 15) * 4;
#pragma unroll
  for (int i = 0; i < 4; ++i) {
    float s = Sp[0][row][c0 + i] + Sp[1][row][c0 + i] +
              Sp[2][row][c0 + i] + Sp[3][row][c0 + i];
    Sp[0][row][c0 + i] = s;
  }
  if (tid < 64) {
    float q4 = qqp[0][tid] + qqp[1][tid] + qqp[2][tid] + qqp[3][tid];
    invq[tid] = 1.f / fmaxf(sqrtf(q4), 1e-12f);
  } else if (tid < 128) {
    int r = tid - 64;
    float k4 = kkp[0][r] + kkp[1][r] + kkp[2][r] + kkp[3][r];
    invk[r] = 1.f / fmaxf(sqrtf(k4), 1e-12f);
  }
  __syncthreads();

  // softmax: 64 rows x 16 segments x 4 cols
  const int seg = tid & 15;
  float fq = temp[h] * invq[row];
  float v[4], pm = -1e30f;
#pragma unroll
  for (int i = 0; i < 4; i++) {
    v[i] = Sp[0][row][seg * 4 + i] * fq * invk[seg * 4 + i];
    pm = fmaxf(pm, v[i]);
  }
  redm[seg][row] = pm;
  __syncthreads();
  float m = -1e30f;
#pragma unroll
  for (int s = 0; s < 16; s++) m = fmaxf(m, redm[s][row]);
  float ps = 0.f;
#pragma unroll
  for (int i = 0; i < 4; i++) { v[i] = __expf(v[i] - m); ps += v[i]; }
  reds[seg][row] = ps;
  __syncthreads();
  float tot = 0.f;
#pragma unroll
  for (int s = 0; s < 16; s++) tot += reds[s][row];
  float inv = 1.f / tot;
  union { ushort4 q; unsigned short s[4]; } u;
#pragma unroll
  for (int i = 0; i < 4; i++) u.s[i] = f2bf(v[i] * inv);
  *(ushort4*)&P[((size_t)bh * 64 + row) * 64 + seg * 4] = u.q;
}

// ---------------- attn_o: O^T[n][d] = sum_e V^T[n][e] P[d][e] ----------------
// Round-7: split nt-loop across 2x blocks (grid bh*8, 32 px/wave) -> 8
// blocks/CU, 32 waves/CU (was 4 blocks/16 waves): more TLP to hide the
// serial V->LDS->MFMA->LDS->store chain.
__launch_bounds__(256)
__global__ void attn_o(const unsigned short* __restrict__ qkv,
                       const unsigned short* __restrict__ P,
                       unsigned short* __restrict__ aoT) {
  int blk = blockIdx.x;
  int nc = blk & 7, bh = blk >> 3;
  int b = bh >> 3, h = bh & 7;
  const unsigned short* V = qkv + ((size_t)b * QKV_M + 2 * CCH + h * 64) * NPIX;
  unsigned short* Ob = aoT + (size_t)b * NPIX * CCH + h * 64;
  int tid = threadIdx.x, lane = tid & 63, wave = tid >> 6;
  int quad = lane >> 4, l16 = lane & 15;

  __shared__ __align__(16) unsigned short Vt[4][16][72];
  __shared__ __align__(16) unsigned short Ot[4][16][72];

  // P fragments (B-operand: row d = j*16+l16, k = e)
  const unsigned short* Pb = P + (size_t)bh * 64 * 64;
  bf16x8 Pf[4][2];
  for (int j = 0; j < 4; j++)
    for (int ks = 0; ks < 2; ks++)
      Pf[j][ks] = *(const bf16x8*)&Pb[(j * 16 + l16) * 64 + ks * 32 + quad * 8];

  f32x4 zero = {0.f, 0.f, 0.f, 0.f};
  int e1 = lane >> 1, noff = (lane & 1) * 8;
  int nbase = nc * 128 + wave * 32;
  int orow = lane >> 3, ocol = (lane & 7) * 8;

  union { uint4 q; unsigned short s[8]; } g0, g1, c0, c1;
  g0.q = *(const uint4*)&V[(size_t)e1 * NPIX + nbase + noff];
  g1.q = *(const uint4*)&V[(size_t)(e1 + 32) * NPIX + nbase + noff];
#pragma unroll
  for (int nt = 0; nt < 2; nt++) {
    int n0 = nbase + nt * 16;
    c0 = g0; c1 = g1;
    if (nt < 1) {
      g0.q = *(const uint4*)&V[(size_t)e1 * NPIX + n0 + 16 + noff];
      g1.q = *(const uint4*)&V[(size_t)(e1 + 32) * NPIX + n0 + 16 + noff];
    }
    for (int jj = 0; jj < 8; jj++) {
      Vt[wave][noff + jj][e1]      = c0.s[jj];
      Vt[wave][noff + jj][e1 + 32] = c1.s[jj];
    }
    bf16x8 Af0 = *(const bf16x8*)&Vt[wave][l16][quad * 8];
    bf16x8 Af1 = *(const bf16x8*)&Vt[wave][l16][32 + quad * 8];
    f32x4 oacc[4];
    for (int j = 0; j < 4; j++) {
      oacc[j] = __builtin_amdgcn_mfma_f32_16x16x32_bf16(Af0, Pf[j][0], zero, 0, 0, 0);
      oacc[j] = __builtin_amdgcn_mfma_f32_16x16x32_bf16(Af1, Pf[j][1], oacc[j], 0, 0, 0);
    }
    for (int j = 0; j < 4; j++)
      for (int r = 0; r < 4; r++)
        Ot[wave][quad * 4 + r][j * 16 + l16] = f2bf(oacc[j][r]);
    uint4 o0 = *(const uint4*)&Ot[wave][orow][ocol];
    uint4 o1 = *(const uint4*)&Ot[wave][orow + 8][ocol];
    *(uint4*)&Ob[(size_t)(n0 + orow) * CCH + ocol] = o0;
    *(uint4*)&Ob[(size_t)(n0 + orow + 8) * CCH + ocol] = o1;
  }
}

// ---------------------------------------------------------------------------
extern "C" void kernel_launch(void* const* d_in, const int* in_sizes, int n_in,
                              void* d_out, int out_size, void* d_ws, size_t ws_size,
                              hipStream_t stream) {
  const float* x     = (const float*)d_in[0];
  const float* Wq    = (const float*)d_in[1];
  const float* Wk    = (const float*)d_in[2];
  const float* Wv    = (const float*)d_in[3];
  const float* dww   = (const float*)d_in[4];
  const float* gamma = (const float*)d_in[5];
  const float* beta  = (const float*)d_in[6];
  const float* temp  = (const float*)d_in[7];
  const float* Wp    = (const float*)d_in[8];
  const float* bp    = (const float*)d_in[9];
  float* out = (float*)d_out;

  char* ws = (char*)d_ws;
  unsigned short* wcat = (unsigned short*)ws;             // [1536,512] bf16
  unsigned short* wpb  = wcat + (size_t)QKV_M * CCH;      // [512,512] bf16
  float* s1 = (float*)(wpb + (size_t)CCH * CCH);
  float* s2 = s1 + CCH;
  unsigned short* Pbuf = (unsigned short*)(s2 + CCH);     // [B*H,64,64] bf16, 2MB
  char* dyn = (char*)(Pbuf + (size_t)BATCH * HEADS * 64 * 64);
  size_t fixed = (size_t)(dyn - ws);
  size_t per_b = ((size_t)NPIX * CCH + (size_t)QKV_M * NPIX) * 2;  // 4 MB/batch
  int BC = BATCH;
  while (BC > 1 && fixed + (size_t)BC * per_b > ws_size) BC >>= 1;
  unsigned short* xT  = (unsigned short*)dyn;                  // [BC,N,C]; reused as aoT
  unsigned short* qkv = xT + (size_t)BC * NPIX * CCH;          // [BC,1536,N]

  convert_w<<<CCH * CCH / 1024, 256, 0, stream>>>(Wq, Wk, Wv, Wp, wcat, wpb);
  hipMemsetAsync(s1, 0, 2 * CCH * sizeof(float), stream);
  dw_stats<<<dim3(CCH, BATCH), 256, 0, stream>>>(x, dww, s1, s2);

  for (int b0 = 0; b0 < BATCH; b0 += BC) {
    const float* xc = x + (size_t)b0 * CCH * NPIX;
    float* outc = out + (size_t)b0 * CCH * NPIX;
    transpose_f2b<<<dim3(NPIX / 64, CCH / 64, BC), 256, 0, stream>>>(xc, xT);
    gemm_bt<false><<<dim3(NPIX / 256, QKV_M / 256, BC), 512, 0, stream>>>(
        wcat, xT, qkv, nullptr, QKV_M, NPIX, CCH);
    attn_s<<<BC * HEADS, 1024, 0, stream>>>(qkv, temp, Pbuf);
    gate_apply<<<dim3(CCH, BC), 256, 0, stream>>>(xc, dww, s1, s2, gamma, beta, qkv);
    attn_o<<<BC * HEADS * 8, 256, 0, stream>>>(qkv, Pbuf, xT);  // aoT overwrites xT
    gemm_bt<true><<<dim3(NPIX / 256, CCH / 256, BC), 512, 0, stream>>>(
        wpb, xT, outc, bp, CCH, NPIX, CCH);
  }
}